// Round 1
// baseline (776.723 us; speedup 1.0000x reference)
//
#include <hip/hip_runtime.h>
#include <math.h>

#define NEG_SLOPE 0.2f

// ---------- helpers ----------
__device__ __forceinline__ unsigned fkey(float x) {
    unsigned b = __float_as_uint(x);
    return (b & 0x80000000u) ? ~b : (b | 0x80000000u);
}
__device__ __forceinline__ float funkey(unsigned k) {
    unsigned b = (k & 0x80000000u) ? (k & 0x7FFFFFFFu) : ~k;
    return __uint_as_float(b);
}
__device__ __forceinline__ float lrelu(float v) { return v > 0.f ? v : NEG_SLOPE * v; }
__device__ __forceinline__ float elu(float v) { return v > 0.f ? v : (expf(v) - 1.f); }

// ---------- init scratch (ws is poisoned 0xAA before every call) ----------
__global__ void init_k(float* s1, float* s2, unsigned* m1u, unsigned* m2u,
                       int* deg, int* cursor, float* gsum, int N) {
    int t = blockIdx.x * blockDim.x + threadIdx.x;
    if (t < N * 8) { s1[t] = 0.f; m1u[t] = 0x007FFFFFu; }  // key(-inf)
    if (t < N)     { s2[t] = 0.f; m2u[t] = 0x007FFFFFu; deg[t] = 0; cursor[t] = 0; }
    if (t < 64)    gsum[t] = 0.f;
}

// ---------- h1 = [ent_emb[x] | rel_emb[edge_type]]  [N,128] ----------
__global__ void build_h_k(const int* __restrict__ x, const int* __restrict__ et,
                          const float* __restrict__ ent_emb, const float* __restrict__ rel_emb,
                          float* __restrict__ h1, int N) {
    int t = blockIdx.x * blockDim.x + threadIdx.x;
    if (t >= N * 128) return;
    int n = t >> 7, j = t & 127;
    float v = (j < 64) ? ent_emb[(size_t)x[n] * 64 + j]
                       : rel_emb[(size_t)et[n] * 64 + (j - 64)];
    h1[t] = v;
}

// ---------- tiled fp32 GEMM: C[M,N] = A[M,K] @ B[K,N]; K,N multiples of 64 ----------
#define LDP 68
__global__ __launch_bounds__(256) void sgemm_k(const float* __restrict__ A,
                                               const float* __restrict__ B,
                                               float* __restrict__ C,
                                               int M, int N, int K) {
    __shared__ float Ast[64 * LDP];  // transposed: Ast[k][r]
    __shared__ float Bs[64 * LDP];   // Bs[k][c]
    int tid = threadIdx.x;
    int tx = tid & 15, ty = tid >> 4;
    int row0 = blockIdx.x * 64;
    int col0 = blockIdx.y * 64;
    float acc[4][4] = {};
    for (int k0 = 0; k0 < K; k0 += 64) {
#pragma unroll
        for (int i = 0; i < 4; i++) {
            int f = tid + i * 256;
            int r = f >> 4, c4 = f & 15;
            int gr = row0 + r;
            float4 v = make_float4(0.f, 0.f, 0.f, 0.f);
            if (gr < M) v = *(const float4*)(A + (size_t)gr * K + k0 + c4 * 4);
            Ast[(c4 * 4 + 0) * LDP + r] = v.x;
            Ast[(c4 * 4 + 1) * LDP + r] = v.y;
            Ast[(c4 * 4 + 2) * LDP + r] = v.z;
            Ast[(c4 * 4 + 3) * LDP + r] = v.w;
        }
#pragma unroll
        for (int i = 0; i < 4; i++) {
            int f = tid + i * 256;
            int kr = f >> 4, c4 = f & 15;
            float4 v = *(const float4*)(B + (size_t)(k0 + kr) * N + col0 + c4 * 4);
            *(float4*)(Bs + kr * LDP + c4 * 4) = v;
        }
        __syncthreads();
#pragma unroll
        for (int kk = 0; kk < 64; kk++) {
            float4 av = *(const float4*)(Ast + kk * LDP + ty * 4);
            float4 bv = *(const float4*)(Bs + kk * LDP + tx * 4);
            float a[4] = {av.x, av.y, av.z, av.w};
            float b[4] = {bv.x, bv.y, bv.z, bv.w};
#pragma unroll
            for (int i = 0; i < 4; i++)
#pragma unroll
                for (int j = 0; j < 4; j++) acc[i][j] += a[i] * b[j];
        }
        __syncthreads();
    }
#pragma unroll
    for (int i = 0; i < 4; i++) {
        int gr = row0 + ty * 4 + i;
        if (gr < M) {
            float4 v = make_float4(acc[i][0], acc[i][1], acc[i][2], acc[i][3]);
            *(float4*)(C + (size_t)gr * N + col0 + tx * 4) = v;
        }
    }
}

// ---------- attention logits: als/ald [N,H] ----------
template <int H>
__global__ void attn_k(const float* __restrict__ hl, const float* __restrict__ as_w,
                       const float* __restrict__ ad_w, float* __restrict__ als,
                       float* __restrict__ ald, int N) {
    int t = blockIdx.x * blockDim.x + threadIdx.x;
    if (t >= N * H) return;
    int n = t / H, h = t % H;
    const float* row = hl + (size_t)n * (H * 64) + h * 64;
    float s_ = 0.f, d_ = 0.f;
#pragma unroll
    for (int c = 0; c < 64; c += 4) {
        float4 r = *(const float4*)(row + c);
        float4 aw = *(const float4*)(as_w + h * 64 + c);
        float4 dw = *(const float4*)(ad_w + h * 64 + c);
        s_ += r.x * aw.x + r.y * aw.y + r.z * aw.z + r.w * aw.w;
        d_ += r.x * dw.x + r.y * dw.y + r.z * dw.z + r.w * dw.w;
    }
    als[t] = s_;
    ald[t] = d_;
}

// ---------- per-edge: max (+degree count, layer1 only via flag) ----------
template <int H>
__global__ void edge_max_k(const int* __restrict__ ei, int E, int N,
                           const float* __restrict__ als, const float* __restrict__ ald,
                           unsigned* __restrict__ mu, int* __restrict__ deg) {
    int e = blockIdx.x * blockDim.x + threadIdx.x;
    if (e >= E + N) return;
    int src = e < E ? ei[e] : e - E;
    int dst = e < E ? ei[E + e] : e - E;
#pragma unroll
    for (int h = 0; h < H; h++) {
        float v = lrelu(als[src * H + h] + ald[dst * H + h]);
        atomicMax(&mu[dst * H + h], fkey(v));
    }
    if (deg) atomicAdd(&deg[dst], 1);
}

// ---------- per-edge: exp + sum ----------
template <int H>
__global__ void edge_exp_k(const int* __restrict__ ei, int E, int N,
                           const float* __restrict__ als, const float* __restrict__ ald,
                           const unsigned* __restrict__ mu, float* __restrict__ ex,
                           float* __restrict__ s) {
    int e = blockIdx.x * blockDim.x + threadIdx.x;
    if (e >= E + N) return;
    int src = e < E ? ei[e] : e - E;
    int dst = e < E ? ei[E + e] : e - E;
#pragma unroll
    for (int h = 0; h < H; h++) {
        float v = lrelu(als[src * H + h] + ald[dst * H + h]);
        float m = funkey(mu[dst * H + h]);
        float xv = expf(v - m);
        ex[(size_t)e * H + h] = xv;
        atomicAdd(&s[dst * H + h], xv);
    }
}

// ---------- single-block scan of degrees -> exclusive offsets ----------
__global__ __launch_bounds__(1024) void scan_k(const int* __restrict__ deg,
                                               int* __restrict__ offs, int N, int Etot) {
    __shared__ int part[1024];
    int t = threadIdx.x;
    const int CH = (N + 1023) / 1024;
    int base = t * CH;
    int sum = 0;
    for (int i = 0; i < CH; i++) {
        int idx = base + i;
        if (idx < N) sum += deg[idx];
    }
    part[t] = sum;
    __syncthreads();
    for (int off = 1; off < 1024; off <<= 1) {
        int v = (t >= off) ? part[t - off] : 0;
        __syncthreads();
        part[t] += v;
        __syncthreads();
    }
    int run = (t == 0) ? 0 : part[t - 1];
    for (int i = 0; i < CH; i++) {
        int idx = base + i;
        if (idx < N) { offs[idx] = run; run += deg[idx]; }
    }
    if (t == 0) offs[N] = Etot;
}

// ---------- CSR fill ----------
__global__ void fill_k(const int* __restrict__ ei, int E, int N,
                       const int* __restrict__ offs, int* __restrict__ cursor,
                       int* __restrict__ csr_eid, int* __restrict__ csr_src) {
    int e = blockIdx.x * blockDim.x + threadIdx.x;
    if (e >= E + N) return;
    int src = e < E ? ei[e] : e - E;
    int dst = e < E ? ei[E + e] : e - E;
    int pos = offs[dst] + atomicAdd(&cursor[dst], 1);
    csr_eid[pos] = e;
    csr_src[pos] = src;
}

// ---------- layer1 aggregate + bias + elu; writes h2 = [out | ent] ----------
__global__ __launch_bounds__(512) void agg1_k(const float* __restrict__ hl1,
                                              const float* __restrict__ ex1,
                                              const float* __restrict__ s1,
                                              const float* __restrict__ b1,
                                              const int* __restrict__ offs,
                                              const int* __restrict__ csr_eid,
                                              const int* __restrict__ csr_src,
                                              const float* __restrict__ h1,
                                              float* __restrict__ h2, int N) {
    int n = blockIdx.x;
    int tid = threadIdx.x;  // 512: h = tid>>6, c = tid&63
    int h = tid >> 6;
    float inv = 1.0f / (s1[n * 8 + h] + 1e-16f);
    int p0 = offs[n], p1 = offs[n + 1];
    float acc = 0.f;
    for (int p = p0; p < p1; p++) {
        int eid = csr_eid[p], sn = csr_src[p];
        acc += ex1[(size_t)eid * 8 + h] * hl1[(size_t)sn * 512 + tid];
    }
    float v = elu(acc * inv + b1[tid]);
    h2[(size_t)n * 576 + tid] = v;
    if (tid < 64) h2[(size_t)n * 576 + 512 + tid] = h1[(size_t)n * 128 + tid];
}

// ---------- layer2 aggregate + bias + elu -> out2 [N,64] ----------
__global__ __launch_bounds__(64) void agg2_k(const float* __restrict__ hl2,
                                             const float* __restrict__ ex2,
                                             const float* __restrict__ s2,
                                             const float* __restrict__ b2,
                                             const int* __restrict__ offs,
                                             const int* __restrict__ csr_eid,
                                             const int* __restrict__ csr_src,
                                             float* __restrict__ out2, int N) {
    int n = blockIdx.x;
    int c = threadIdx.x;
    float inv = 1.f / (s2[n] + 1e-16f);
    int p0 = offs[n], p1 = offs[n + 1];
    float acc = 0.f;
    for (int p = p0; p < p1; p++)
        acc += ex2[csr_eid[p]] * hl2[(size_t)csr_src[p] * 64 + c];
    out2[(size_t)n * 64 + c] = elu(acc * inv + b2[c]);
}

// ---------- column reduce: gsum[c] = sum_n out2[n,c] ----------
__global__ __launch_bounds__(64) void colred_k(const float* __restrict__ out2,
                                               float* __restrict__ gsum, int N) {
    int c = threadIdx.x;
    int n0 = blockIdx.x * 256;
    int n1 = min(n0 + 256, N);
    float acc = 0.f;
    for (int n = n0; n < n1; n++) acc += out2[(size_t)n * 64 + c];
    atomicAdd(&gsum[c], acc);
}

// ---------- final: out = (gsum/N) @ fc_w + fc_b ----------
__global__ __launch_bounds__(256) void final_k(const float* __restrict__ gsum,
                                               const float* __restrict__ fcw,
                                               const float* __restrict__ fcb,
                                               float* __restrict__ out, int N) {
    __shared__ float g[64];
    int t = threadIdx.x;
    if (t < 64) g[t] = gsum[t] / (float)N;
    __syncthreads();
    if (t < 200) {
        float acc = fcb[t];
#pragma unroll
        for (int c = 0; c < 64; c++) acc += g[c] * fcw[c * 200 + t];
        out[t] = acc;
    }
}

extern "C" void kernel_launch(void* const* d_in, const int* in_sizes, int n_in,
                              void* d_out, int out_size, void* d_ws, size_t ws_size,
                              hipStream_t stream) {
    const int* x = (const int*)d_in[0];
    const int* ei = (const int*)d_in[1];
    const int* et = (const int*)d_in[2];
    const float* ent_emb = (const float*)d_in[3];
    const float* rel_emb = (const float*)d_in[4];
    const float* W1 = (const float*)d_in[5];
    const float* a1s = (const float*)d_in[6];
    const float* a1d = (const float*)d_in[7];
    const float* b1 = (const float*)d_in[8];
    const float* W2 = (const float*)d_in[9];
    const float* a2s = (const float*)d_in[10];
    const float* a2d = (const float*)d_in[11];
    const float* b2 = (const float*)d_in[12];
    const float* fcw = (const float*)d_in[13];
    const float* fcb = (const float*)d_in[14];
    float* out = (float*)d_out;

    int N = in_sizes[0];
    int E = in_sizes[1] / 2;
    int Etot = E + N;

    char* p = (char*)d_ws;
    auto alloc = [&](size_t bytes) -> char* {
        char* r = p;
        p += (bytes + 255) & ~(size_t)255;
        return r;
    };
    float* h1   = (float*)alloc((size_t)N * 128 * 4);
    float* hl1  = (float*)alloc((size_t)N * 512 * 4);
    float* als1 = (float*)alloc((size_t)N * 8 * 4);
    float* ald1 = (float*)alloc((size_t)N * 8 * 4);
    unsigned* m1u = (unsigned*)alloc((size_t)N * 8 * 4);
    float* s1   = (float*)alloc((size_t)N * 8 * 4);
    float* ex1  = (float*)alloc((size_t)Etot * 8 * 4);
    float* h2   = (float*)alloc((size_t)N * 576 * 4);
    float* hl2  = (float*)alloc((size_t)N * 64 * 4);
    float* als2 = (float*)alloc((size_t)N * 4);
    float* ald2 = (float*)alloc((size_t)N * 4);
    unsigned* m2u = (unsigned*)alloc((size_t)N * 4);
    float* s2   = (float*)alloc((size_t)N * 4);
    float* ex2  = (float*)alloc((size_t)Etot * 4);
    float* out2 = (float*)alloc((size_t)N * 64 * 4);
    float* gsum = (float*)alloc(64 * 4);
    int* deg    = (int*)alloc((size_t)N * 4);
    int* offs   = (int*)alloc((size_t)(N + 1) * 4);
    int* cursor = (int*)alloc((size_t)N * 4);
    int* csr_eid = (int*)alloc((size_t)Etot * 4);
    int* csr_src = (int*)alloc((size_t)Etot * 4);

    int tb = 256;
    // init scratch
    init_k<<<(N * 8 + tb - 1) / tb, tb, 0, stream>>>(s1, s2, m1u, m2u, deg, cursor, gsum, N);
    // h1
    build_h_k<<<(N * 128 + tb - 1) / tb, tb, 0, stream>>>(x, et, ent_emb, rel_emb, h1, N);
    // GEMM1: hl1[N,512] = h1[N,128] @ W1[128,512]
    sgemm_k<<<dim3((N + 63) / 64, 512 / 64), 256, 0, stream>>>(h1, W1, hl1, N, 512, 128);
    // attention logits layer1
    attn_k<8><<<(N * 8 + tb - 1) / tb, tb, 0, stream>>>(hl1, a1s, a1d, als1, ald1, N);
    // edge max (+degree)
    edge_max_k<8><<<(Etot + tb - 1) / tb, tb, 0, stream>>>(ei, E, N, als1, ald1, m1u, deg);
    // edge exp + denom
    edge_exp_k<8><<<(Etot + tb - 1) / tb, tb, 0, stream>>>(ei, E, N, als1, ald1, m1u, ex1, s1);
    // CSR build
    scan_k<<<1, 1024, 0, stream>>>(deg, offs, N, Etot);
    fill_k<<<(Etot + tb - 1) / tb, tb, 0, stream>>>(ei, E, N, offs, cursor, csr_eid, csr_src);
    // aggregate layer1 -> h2
    agg1_k<<<N, 512, 0, stream>>>(hl1, ex1, s1, b1, offs, csr_eid, csr_src, h1, h2, N);
    // GEMM2: hl2[N,64] = h2[N,576] @ W2[576,64]
    sgemm_k<<<dim3((N + 63) / 64, 1), 256, 0, stream>>>(h2, W2, hl2, N, 64, 576);
    // attention logits layer2
    attn_k<1><<<(N + tb - 1) / tb, tb, 0, stream>>>(hl2, a2s, a2d, als2, ald2, N);
    edge_max_k<1><<<(Etot + tb - 1) / tb, tb, 0, stream>>>(ei, E, N, als2, ald2, m2u, nullptr);
    edge_exp_k<1><<<(Etot + tb - 1) / tb, tb, 0, stream>>>(ei, E, N, als2, ald2, m2u, ex2, s2);
    // aggregate layer2 -> out2
    agg2_k<<<N, 64, 0, stream>>>(hl2, ex2, s2, b2, offs, csr_eid, csr_src, out2, N);
    // mean-pool reduce
    colred_k<<<(N + 255) / 256, 64, 0, stream>>>(out2, gsum, N);
    // final linear
    final_k<<<1, 256, 0, stream>>>(gsum, fcw, fcb, out, N);
}

// Round 2
// 414.650 us; speedup vs baseline: 1.8732x; 1.8732x over previous
//
#include <hip/hip_runtime.h>
#include <math.h>

#define NEG_SLOPE 0.2f

typedef __attribute__((ext_vector_type(8))) short short8;   // 8 bf16 (4 VGPRs)
typedef __attribute__((ext_vector_type(4))) float f32x4;

// ---------- helpers ----------
__device__ __forceinline__ float lrelu(float v) { return v > 0.f ? v : NEG_SLOPE * v; }
__device__ __forceinline__ float elu(float v) { return v > 0.f ? v : (__expf(v) - 1.f); }
__device__ __forceinline__ unsigned short f2b(float f) {   // fp32 -> bf16 RNE
    unsigned u = __float_as_uint(f);
    return (unsigned short)((u + 0x7FFFu + ((u >> 16) & 1u)) >> 16);
}
__device__ __forceinline__ float blo(unsigned v) { return __uint_as_float(v << 16); }
__device__ __forceinline__ float bhi(unsigned v) { return __uint_as_float(v & 0xFFFF0000u); }
__device__ __forceinline__ unsigned packb(float a, float b) {
    return ((unsigned)f2b(b) << 16) | (unsigned)f2b(a);
}
// LDS xor-swizzle: 16B-chunk o within a row r -> conflict-free-ish placement
__device__ __forceinline__ int sw(int r, int o) { return (o ^ (r & 7)) << 3; }

// ---------- prep: init scratch + build h1(bf16) + transpose weights to bf16 ----------
__global__ void prep_k(const int* __restrict__ x, const int* __restrict__ et,
                       const float* __restrict__ ent_emb, const float* __restrict__ rel_emb,
                       const float* __restrict__ W1, const float* __restrict__ W2,
                       unsigned short* __restrict__ h1b, unsigned short* __restrict__ W1t,
                       unsigned short* __restrict__ W2t, int* __restrict__ deg,
                       int* __restrict__ cursor, float* __restrict__ gsum, int N) {
    int t = blockIdx.x * blockDim.x + threadIdx.x;
    if (t < N * 128) {
        int n = t >> 7, j = t & 127;
        float v = (j < 64) ? ent_emb[(size_t)x[n] * 64 + j]
                           : rel_emb[(size_t)et[n] * 64 + (j - 64)];
        h1b[t] = f2b(v);
    }
    if (t < 512 * 128) {  // W1t[n][k] = W1[k][n]
        int n = t >> 7, k = t & 127;
        W1t[t] = f2b(W1[(size_t)k * 512 + n]);
    }
    if (t < 64 * 576) {   // W2t[n][k] = W2[k][n]
        int n = t / 576, k = t % 576;
        W2t[t] = f2b(W2[(size_t)k * 64 + n]);
    }
    if (t < N) { deg[t] = 0; cursor[t] = 0; }
    if (t < 64) gsum[t] = 0.f;
}

// ---------- GEMM1: hl1[M,512](bf16) = h1[M,128](bf16) @ W1t[512,128]^T ----------
__global__ __launch_bounds__(256) void gemm1_k(const unsigned short* __restrict__ A,
                                               const unsigned short* __restrict__ Bt,
                                               unsigned short* __restrict__ Cb, int M) {
    __shared__ __align__(16) unsigned short As[128 * 128];
    __shared__ __align__(16) unsigned short Bs[128 * 128];
    int tid = threadIdx.x;
    int m0 = blockIdx.x * 128, n0 = blockIdx.y * 128;
    // stage A: 128 rows x 128 k, 16B chunks
    for (int c = tid; c < 2048; c += 256) {
        int r = c >> 4, o = c & 15;
        int gr = m0 + r;
        uint4 v = make_uint4(0u, 0u, 0u, 0u);
        if (gr < M) v = *(const uint4*)(A + (size_t)gr * 128 + o * 8);
        *(uint4*)(As + r * 128 + sw(r, o)) = v;
    }
    for (int c = tid; c < 2048; c += 256) {
        int r = c >> 4, o = c & 15;
        uint4 v = *(const uint4*)(Bt + (size_t)(n0 + r) * 128 + o * 8);
        *(uint4*)(Bs + r * 128 + sw(r, o)) = v;
    }
    __syncthreads();
    int w = tid >> 6, lane = tid & 63;
    int wr = (w >> 1) * 64, wc = (w & 1) * 64;
    int m16 = lane & 15, quad = lane >> 4;
    f32x4 acc[4][4] = {};
#pragma unroll
    for (int kk = 0; kk < 128; kk += 32) {
        int ob = (kk >> 3) + quad;   // 16B chunk index for this quad
        short8 a[4], b[4];
#pragma unroll
        for (int i = 0; i < 4; i++) {
            int r = wr + i * 16 + m16;
            a[i] = *(const short8*)(As + r * 128 + sw(r, ob));
        }
#pragma unroll
        for (int j = 0; j < 4; j++) {
            int r = wc + j * 16 + m16;
            b[j] = *(const short8*)(Bs + r * 128 + sw(r, ob));
        }
#pragma unroll
        for (int i = 0; i < 4; i++)
#pragma unroll
            for (int j = 0; j < 4; j++)
                acc[i][j] = __builtin_amdgcn_mfma_f32_16x16x32_bf16(a[i], b[j], acc[i][j], 0, 0, 0);
    }
#pragma unroll
    for (int i = 0; i < 4; i++)
#pragma unroll
        for (int j = 0; j < 4; j++)
#pragma unroll
            for (int reg = 0; reg < 4; reg++) {
                int row = m0 + wr + i * 16 + quad * 4 + reg;
                int col = n0 + wc + j * 16 + m16;
                if (row < M) Cb[(size_t)row * 512 + col] = f2b(acc[i][j][reg]);
            }
}

// ---------- GEMM2: hl2[M,64](bf16) = h2[M,576](bf16) @ W2t[64,576]^T ----------
__global__ __launch_bounds__(256) void gemm2_k(const unsigned short* __restrict__ A,
                                               const unsigned short* __restrict__ Bt,
                                               unsigned short* __restrict__ Cb, int M) {
    __shared__ __align__(16) unsigned short As[128 * 64];
    __shared__ __align__(16) unsigned short Bs[64 * 64];
    int tid = threadIdx.x;
    int m0 = blockIdx.x * 128;
    int w = tid >> 6, lane = tid & 63;
    int wr = (w >> 1) * 64, wc = (w & 1) * 32;
    int m16 = lane & 15, quad = lane >> 4;
    f32x4 acc[4][2] = {};
    for (int k0 = 0; k0 < 576; k0 += 64) {
        __syncthreads();
        for (int c = tid; c < 1024; c += 256) {  // A: 128 rows x 64k
            int r = c >> 3, o = c & 7;
            int gr = m0 + r;
            uint4 v = make_uint4(0u, 0u, 0u, 0u);
            if (gr < M) v = *(const uint4*)(A + (size_t)gr * 576 + k0 + o * 8);
            *(uint4*)(As + r * 64 + sw(r, o)) = v;
        }
        for (int c = tid; c < 512; c += 256) {   // B: 64 cols x 64k
            int r = c >> 3, o = c & 7;
            uint4 v = *(const uint4*)(Bt + (size_t)r * 576 + k0 + o * 8);
            *(uint4*)(Bs + r * 64 + sw(r, o)) = v;
        }
        __syncthreads();
#pragma unroll
        for (int kk = 0; kk < 64; kk += 32) {
            int ob = (kk >> 3) + quad;
            short8 b[2];
#pragma unroll
            for (int j = 0; j < 2; j++) {
                int r = wc + j * 16 + m16;
                b[j] = *(const short8*)(Bs + r * 64 + sw(r, ob));
            }
#pragma unroll
            for (int i = 0; i < 4; i++) {
                int r = wr + i * 16 + m16;
                short8 a = *(const short8*)(As + r * 64 + sw(r, ob));
#pragma unroll
                for (int j = 0; j < 2; j++)
                    acc[i][j] = __builtin_amdgcn_mfma_f32_16x16x32_bf16(a, b[j], acc[i][j], 0, 0, 0);
            }
        }
    }
#pragma unroll
    for (int i = 0; i < 4; i++)
#pragma unroll
        for (int j = 0; j < 2; j++)
#pragma unroll
            for (int reg = 0; reg < 4; reg++) {
                int row = m0 + wr + i * 16 + quad * 4 + reg;
                int col = wc + j * 16 + m16;
                if (row < M) Cb[(size_t)row * 64 + col] = f2b(acc[i][j][reg]);
            }
}

// ---------- attention logits ----------
template <int H>
__global__ void attn_k(const unsigned short* __restrict__ hl, const float* __restrict__ aw_s,
                       const float* __restrict__ aw_d, float* __restrict__ als,
                       float* __restrict__ ald, int N) {
    int t = blockIdx.x * blockDim.x + threadIdx.x;
    if (t >= N * H) return;
    int n = t / H, h = t % H;
    const unsigned short* row = hl + (size_t)n * (H * 64) + h * 64;
    float s_ = 0.f, d_ = 0.f;
#pragma unroll
    for (int c = 0; c < 64; c += 2) {
        unsigned v = *(const unsigned*)(row + c);
        float f0 = blo(v), f1 = bhi(v);
        s_ += f0 * aw_s[h * 64 + c] + f1 * aw_s[h * 64 + c + 1];
        d_ += f0 * aw_d[h * 64 + c] + f1 * aw_d[h * 64 + c + 1];
    }
    als[t] = s_;
    ald[t] = d_;
}

// ---------- per-edge: ex = exp(lrelu(logit)) (no max shift; logits are O(1)) ----------
template <int H>
__global__ void edge_k(const int* __restrict__ ei, int E, int N,
                       const float* __restrict__ als, const float* __restrict__ ald,
                       float* __restrict__ ex, int* __restrict__ deg) {
    int e = blockIdx.x * blockDim.x + threadIdx.x;
    if (e >= E + N) return;
    int src = e < E ? ei[e] : e - E;
    int dst = e < E ? ei[E + e] : e - E;
#pragma unroll
    for (int h = 0; h < H; h++) {
        float v = lrelu(als[src * H + h] + ald[dst * H + h]);
        ex[(size_t)e * H + h] = __expf(v);
    }
    if (deg) atomicAdd(&deg[dst], 1);
}

// ---------- single-block scan of degrees -> exclusive offsets ----------
__global__ __launch_bounds__(1024) void scan_k(const int* __restrict__ deg,
                                               int* __restrict__ offs, int N, int Etot) {
    __shared__ int part[1024];
    int t = threadIdx.x;
    const int CH = (N + 1023) / 1024;
    int base = t * CH;
    int sum = 0;
    for (int i = 0; i < CH; i++) {
        int idx = base + i;
        if (idx < N) sum += deg[idx];
    }
    part[t] = sum;
    __syncthreads();
    for (int off = 1; off < 1024; off <<= 1) {
        int v = (t >= off) ? part[t - off] : 0;
        __syncthreads();
        part[t] += v;
        __syncthreads();
    }
    int run = (t == 0) ? 0 : part[t - 1];
    for (int i = 0; i < CH; i++) {
        int idx = base + i;
        if (idx < N) { offs[idx] = run; run += deg[idx]; }
    }
    if (t == 0) offs[N] = Etot;
}

// ---------- CSR fill: csr[pos] = {eid, src} ----------
__global__ void fill_k(const int* __restrict__ ei, int E, int N,
                       const int* __restrict__ offs, int* __restrict__ cursor,
                       int2* __restrict__ csr) {
    int e = blockIdx.x * blockDim.x + threadIdx.x;
    if (e >= E + N) return;
    int src = e < E ? ei[e] : e - E;
    int dst = e < E ? ei[E + e] : e - E;
    int pos = offs[dst] + atomicAdd(&cursor[dst], 1);
    csr[pos] = make_int2(e, src);
}

// ---------- layer1 aggregate + softmax-normalize + bias + elu -> h2 = [out|ent] bf16 ----------
__global__ __launch_bounds__(256) void agg1_k(const unsigned short* __restrict__ hl1,
                                              const float* __restrict__ ex1,
                                              const float* __restrict__ b1,
                                              const int* __restrict__ offs,
                                              const int2* __restrict__ csr,
                                              const unsigned short* __restrict__ h1b,
                                              unsigned short* __restrict__ h2, int N) {
    int n = blockIdx.x;
    int t = threadIdx.x;            // 256: h = t>>5, col-pair = (t&31)*2
    int h = t >> 5;
    int col = h * 64 + (t & 31) * 2;
    int p0 = offs[n], p1 = offs[n + 1];
    float a0 = 0.f, a1 = 0.f, ssum = 0.f;
    for (int p = p0; p < p1; p++) {
        int2 es = csr[p];
        float xv = ex1[(size_t)es.x * 8 + h];
        unsigned v = *(const unsigned*)(hl1 + (size_t)es.y * 512 + col);
        ssum += xv;
        a0 += xv * blo(v);
        a1 += xv * bhi(v);
    }
    float inv = 1.f / (ssum + 1e-16f);
    float v0 = elu(a0 * inv + b1[col]);
    float v1 = elu(a1 * inv + b1[col + 1]);
    *(unsigned*)(h2 + (size_t)n * 576 + col) = packb(v0, v1);
    if (t < 32)  // append ent (first 64 cols of h1b)
        *(unsigned*)(h2 + (size_t)n * 576 + 512 + 2 * t) =
            *(const unsigned*)(h1b + (size_t)n * 128 + 2 * t);
}

// ---------- layer2 aggregate + normalize + bias + elu -> out2 fp32 ----------
__global__ __launch_bounds__(64) void agg2_k(const unsigned short* __restrict__ hl2,
                                             const float* __restrict__ ex2,
                                             const float* __restrict__ b2,
                                             const int* __restrict__ offs,
                                             const int2* __restrict__ csr,
                                             float* __restrict__ out2, int N) {
    int n = blockIdx.x;
    int t = threadIdx.x;
    if (t >= 32) return;
    int p0 = offs[n], p1 = offs[n + 1];
    float a0 = 0.f, a1 = 0.f, ssum = 0.f;
    for (int p = p0; p < p1; p++) {
        int2 es = csr[p];
        float xv = ex2[es.x];
        unsigned v = *(const unsigned*)(hl2 + (size_t)es.y * 64 + 2 * t);
        ssum += xv;
        a0 += xv * blo(v);
        a1 += xv * bhi(v);
    }
    float inv = 1.f / (ssum + 1e-16f);
    float v0 = elu(a0 * inv + b2[2 * t]);
    float v1 = elu(a1 * inv + b2[2 * t + 1]);
    *(float2*)(out2 + (size_t)n * 64 + 2 * t) = make_float2(v0, v1);
}

// ---------- column reduce ----------
__global__ __launch_bounds__(64) void colred_k(const float* __restrict__ out2,
                                               float* __restrict__ gsum, int N) {
    int c = threadIdx.x;
    int n0 = blockIdx.x * 256;
    int n1 = min(n0 + 256, N);
    float acc = 0.f;
    for (int n = n0; n < n1; n++) acc += out2[(size_t)n * 64 + c];
    atomicAdd(&gsum[c], acc);
}

// ---------- final linear ----------
__global__ __launch_bounds__(256) void final_k(const float* __restrict__ gsum,
                                               const float* __restrict__ fcw,
                                               const float* __restrict__ fcb,
                                               float* __restrict__ out, int N) {
    __shared__ float g[64];
    int t = threadIdx.x;
    if (t < 64) g[t] = gsum[t] / (float)N;
    __syncthreads();
    if (t < 200) {
        float acc = fcb[t];
#pragma unroll
        for (int c = 0; c < 64; c++) acc += g[c] * fcw[c * 200 + t];
        out[t] = acc;
    }
}

extern "C" void kernel_launch(void* const* d_in, const int* in_sizes, int n_in,
                              void* d_out, int out_size, void* d_ws, size_t ws_size,
                              hipStream_t stream) {
    const int* x = (const int*)d_in[0];
    const int* ei = (const int*)d_in[1];
    const int* et = (const int*)d_in[2];
    const float* ent_emb = (const float*)d_in[3];
    const float* rel_emb = (const float*)d_in[4];
    const float* W1 = (const float*)d_in[5];
    const float* a1s = (const float*)d_in[6];
    const float* a1d = (const float*)d_in[7];
    const float* b1 = (const float*)d_in[8];
    const float* W2 = (const float*)d_in[9];
    const float* a2s = (const float*)d_in[10];
    const float* a2d = (const float*)d_in[11];
    const float* b2 = (const float*)d_in[12];
    const float* fcw = (const float*)d_in[13];
    const float* fcb = (const float*)d_in[14];
    float* out = (float*)d_out;

    int N = in_sizes[0];
    int E = in_sizes[1] / 2;
    int Etot = E + N;

    char* p = (char*)d_ws;
    auto alloc = [&](size_t bytes) -> char* {
        char* r = p;
        p += (bytes + 255) & ~(size_t)255;
        return r;
    };
    unsigned short* h1b = (unsigned short*)alloc((size_t)N * 128 * 2);
    unsigned short* W1t = (unsigned short*)alloc((size_t)512 * 128 * 2);
    unsigned short* W2t = (unsigned short*)alloc((size_t)64 * 576 * 2);
    unsigned short* hl1 = (unsigned short*)alloc((size_t)N * 512 * 2);
    float* als1 = (float*)alloc((size_t)N * 8 * 4);
    float* ald1 = (float*)alloc((size_t)N * 8 * 4);
    float* ex1  = (float*)alloc((size_t)Etot * 8 * 4);
    unsigned short* h2  = (unsigned short*)alloc((size_t)N * 576 * 2);
    unsigned short* hl2 = (unsigned short*)alloc((size_t)N * 64 * 2);
    float* als2 = (float*)alloc((size_t)N * 4);
    float* ald2 = (float*)alloc((size_t)N * 4);
    float* ex2  = (float*)alloc((size_t)Etot * 4);
    float* out2 = (float*)alloc((size_t)N * 64 * 4);
    float* gsum = (float*)alloc(64 * 4);
    int* deg    = (int*)alloc((size_t)N * 4);
    int* offs   = (int*)alloc((size_t)(N + 1) * 4);
    int* cursor = (int*)alloc((size_t)N * 4);
    int2* csr   = (int2*)alloc((size_t)Etot * 8);

    int tb = 256;
    prep_k<<<(N * 128 + tb - 1) / tb, tb, 0, stream>>>(x, et, ent_emb, rel_emb, W1, W2,
                                                       h1b, W1t, W2t, deg, cursor, gsum, N);
    gemm1_k<<<dim3((N + 127) / 128, 4), 256, 0, stream>>>(h1b, W1t, hl1, N);
    attn_k<8><<<(N * 8 + tb - 1) / tb, tb, 0, stream>>>(hl1, a1s, a1d, als1, ald1, N);
    edge_k<8><<<(Etot + tb - 1) / tb, tb, 0, stream>>>(ei, E, N, als1, ald1, ex1, deg);
    scan_k<<<1, 1024, 0, stream>>>(deg, offs, N, Etot);
    fill_k<<<(Etot + tb - 1) / tb, tb, 0, stream>>>(ei, E, N, offs, cursor, csr);
    agg1_k<<<N, 256, 0, stream>>>(hl1, ex1, b1, offs, csr, h1b, h2, N);
    gemm2_k<<<(N + 127) / 128, 256, 0, stream>>>(h2, W2t, hl2, N);
    attn_k<1><<<(N + tb - 1) / tb, tb, 0, stream>>>(hl2, a2s, a2d, als2, ald2, N);
    edge_k<1><<<(Etot + tb - 1) / tb, tb, 0, stream>>>(ei, E, N, als2, ald2, ex2, nullptr);
    agg2_k<<<N, 64, 0, stream>>>(hl2, ex2, b2, offs, csr, out2, N);
    colred_k<<<(N + 255) / 256, 64, 0, stream>>>(out2, gsum, N);
    final_k<<<1, 256, 0, stream>>>(gsum, fcw, fcb, out, N);
}

// Round 3
// 382.113 us; speedup vs baseline: 2.0327x; 1.0851x over previous
//
#include <hip/hip_runtime.h>
#include <math.h>

#define NEG_SLOPE 0.2f

typedef __attribute__((ext_vector_type(8))) short short8;   // 8 bf16 (4 VGPRs)
typedef __attribute__((ext_vector_type(4))) float f32x4;

// ---------- helpers ----------
__device__ __forceinline__ float lrelu(float v) { return v > 0.f ? v : NEG_SLOPE * v; }
__device__ __forceinline__ float elu(float v) { return v > 0.f ? v : (__expf(v) - 1.f); }
__device__ __forceinline__ unsigned short f2b(float f) {   // fp32 -> bf16 RNE
    unsigned u = __float_as_uint(f);
    return (unsigned short)((u + 0x7FFFu + ((u >> 16) & 1u)) >> 16);
}
__device__ __forceinline__ float blo(unsigned v) { return __uint_as_float(v << 16); }
__device__ __forceinline__ float bhi(unsigned v) { return __uint_as_float(v & 0xFFFF0000u); }
__device__ __forceinline__ unsigned packb(float a, float b) {
    return ((unsigned)f2b(b) << 16) | (unsigned)f2b(a);
}
// LDS xor-swizzle: 16B-chunk o within row r
__device__ __forceinline__ int sw(int r, int o) { return (o ^ (r & 7)) << 3; }

// ---------- prep: h1(bf16), projected attn vecs ws1/wd1, W2 transpose, scratch init ----------
__global__ void prep_k(const int* __restrict__ x, const int* __restrict__ et,
                       const float* __restrict__ ent_emb, const float* __restrict__ rel_emb,
                       const float* __restrict__ W1, const float* __restrict__ W2,
                       const float* __restrict__ a1s, const float* __restrict__ a1d,
                       unsigned short* __restrict__ h1b, float* __restrict__ ws1,
                       float* __restrict__ wd1, unsigned short* __restrict__ W2t,
                       int* __restrict__ deg, int* __restrict__ cursor,
                       float* __restrict__ gsum, int N) {
    int t = blockIdx.x * blockDim.x + threadIdx.x;
    if (t < N * 128) {
        int n = t >> 7, j = t & 127;
        float v = (j < 64) ? ent_emb[(size_t)x[n] * 64 + j]
                           : rel_emb[(size_t)et[n] * 64 + (j - 64)];
        h1b[t] = f2b(v);
    }
    if (t < 1024) {  // ws1[k*8+h] = sum_c W1[k][h*64+c]*a1s[h][c]
        int k = t >> 3, h = t & 7;
        float s_ = 0.f, d_ = 0.f;
        const float* wr = W1 + (size_t)k * 512 + h * 64;
#pragma unroll 16
        for (int c = 0; c < 64; c++) {
            s_ += wr[c] * a1s[h * 64 + c];
            d_ += wr[c] * a1d[h * 64 + c];
        }
        ws1[t] = s_;
        wd1[t] = d_;
    }
    if (t < 64 * 576) {   // W2t[n][k] = W2[k][n]
        int n = t / 576, k = t % 576;
        W2t[t] = f2b(W2[(size_t)k * 64 + n]);
    }
    if (t < N) { deg[t] = 0; cursor[t] = 0; }
    if (t < 64) gsum[t] = 0.f;
}

// ---------- layer1 attn logits: als/ald[n,h] = h1[n] . ws1[:,h] ----------
__global__ void attn1_k(const unsigned* __restrict__ h1u, const float* __restrict__ ws1,
                        const float* __restrict__ wd1, float* __restrict__ als,
                        float* __restrict__ ald, int N) {
    int t = blockIdx.x * blockDim.x + threadIdx.x;
    if (t >= N * 8) return;
    int n = t >> 3, h = t & 7;
    float s_ = 0.f, d_ = 0.f;
#pragma unroll 8
    for (int kk = 0; kk < 64; kk++) {
        unsigned v = h1u[(size_t)n * 64 + kk];
        float f0 = blo(v), f1 = bhi(v);
        s_ += f0 * ws1[(2 * kk) * 8 + h] + f1 * ws1[(2 * kk + 1) * 8 + h];
        d_ += f0 * wd1[(2 * kk) * 8 + h] + f1 * wd1[(2 * kk + 1) * 8 + h];
    }
    als[t] = s_;
    ald[t] = d_;
}

// ---------- per-edge: ex = exp(lrelu(logit)), optional degree count ----------
template <int H>
__global__ void edge_k(const int* __restrict__ ei, int E, int N,
                       const float* __restrict__ als, const float* __restrict__ ald,
                       float* __restrict__ ex, int* __restrict__ deg) {
    int e = blockIdx.x * blockDim.x + threadIdx.x;
    if (e >= E + N) return;
    int src = e < E ? ei[e] : e - E;
    int dst = e < E ? ei[E + e] : e - E;
#pragma unroll
    for (int h = 0; h < H; h++) {
        float v = lrelu(als[src * H + h] + ald[dst * H + h]);
        ex[(size_t)e * H + h] = __expf(v);
    }
    if (deg) atomicAdd(&deg[dst], 1);
}

// ---------- single-block scan of degrees -> exclusive offsets ----------
__global__ __launch_bounds__(1024) void scan_k(const int* __restrict__ deg,
                                               int* __restrict__ offs, int N, int Etot) {
    __shared__ int part[1024];
    int t = threadIdx.x;
    const int CH = (N + 1023) / 1024;
    int base = t * CH;
    int sum = 0;
    for (int i = 0; i < CH; i++) {
        int idx = base + i;
        if (idx < N) sum += deg[idx];
    }
    part[t] = sum;
    __syncthreads();
    for (int off = 1; off < 1024; off <<= 1) {
        int v = (t >= off) ? part[t - off] : 0;
        __syncthreads();
        part[t] += v;
        __syncthreads();
    }
    int run = (t == 0) ? 0 : part[t - 1];
    for (int i = 0; i < CH; i++) {
        int idx = base + i;
        if (idx < N) { offs[idx] = run; run += deg[idx]; }
    }
    if (t == 0) offs[N] = Etot;
}

// ---------- CSR fill ----------
__global__ void fill_k(const int* __restrict__ ei, int E, int N,
                       const int* __restrict__ offs, int* __restrict__ cursor,
                       int2* __restrict__ csr) {
    int e = blockIdx.x * blockDim.x + threadIdx.x;
    if (e >= E + N) return;
    int src = e < E ? ei[e] : e - E;
    int dst = e < E ? ei[E + e] : e - E;
    int pos = offs[dst] + atomicAdd(&cursor[dst], 1);
    csr[pos] = make_int2(e, src);
}

// ---------- aggG: G[n][h][k] = (sum_e ex^h h1[src_e][k]) / sum_e ex^h  (bf16) ----------
// one wave per dst node; lane t handles k = 2t,2t+1; also copies ent tail into h2.
__global__ __launch_bounds__(64) void aggG_k(const unsigned* __restrict__ h1u,
                                             const float* __restrict__ ex1,
                                             const int* __restrict__ offs,
                                             const int2* __restrict__ csr,
                                             unsigned* __restrict__ Gu,
                                             unsigned* __restrict__ h2u, int N) {
    int n = blockIdx.x;
    int t = threadIdx.x;
    int p0 = offs[n], p1 = offs[n + 1];
    float a0[8] = {}, a1[8] = {}, ssum[8] = {};
    for (int p = p0; p < p1; p++) {
        int2 es = csr[p];
        float4 e0 = *(const float4*)(ex1 + (size_t)es.x * 8);
        float4 e1 = *(const float4*)(ex1 + (size_t)es.x * 8 + 4);
        float exv[8] = {e0.x, e0.y, e0.z, e0.w, e1.x, e1.y, e1.z, e1.w};
        unsigned hv = h1u[(size_t)es.y * 64 + t];
        float f0 = blo(hv), f1 = bhi(hv);
#pragma unroll
        for (int h = 0; h < 8; h++) {
            a0[h] += exv[h] * f0;
            a1[h] += exv[h] * f1;
            ssum[h] += exv[h];
        }
    }
#pragma unroll
    for (int h = 0; h < 8; h++) {
        float inv = 1.f / (ssum[h] + 1e-16f);
        Gu[(size_t)n * 512 + h * 64 + t] = packb(a0[h] * inv, a1[h] * inv);
    }
    if (t < 32)  // ent tail: h2 cols 512..575 = h1 cols 0..63
        h2u[(size_t)n * 288 + 256 + t] = h1u[(size_t)n * 64 + t];
}

// ---------- gemmG: h2[n][h*64+j] = elu(G[n][h] . W1t[h*64+j] + b1)  per-head GEMM ----------
__global__ __launch_bounds__(256) void gemmG_k(const unsigned short* __restrict__ Gb,
                                               const unsigned short* __restrict__ W1t,
                                               const float* __restrict__ b1,
                                               unsigned short* __restrict__ h2, int M) {
    __shared__ __align__(16) unsigned short As[128 * 128];
    __shared__ __align__(16) unsigned short Bs[64 * 128];
    int tid = threadIdx.x;
    int m0 = blockIdx.x * 128, h = blockIdx.y;
    for (int c = tid; c < 2048; c += 256) {  // A: 128 node-rows x 128 k
        int r = c >> 4, o = c & 15;
        int gr = m0 + r;
        uint4 v = make_uint4(0u, 0u, 0u, 0u);
        if (gr < M) v = *(const uint4*)(Gb + (size_t)gr * 1024 + h * 128 + o * 8);
        *(uint4*)(As + r * 128 + sw(r, o)) = v;
    }
    for (int c = tid; c < 1024; c += 256) {  // B: 64 col-rows x 128 k
        int r = c >> 4, o = c & 15;
        uint4 v = *(const uint4*)(W1t + (size_t)(h * 64 + r) * 128 + o * 8);
        *(uint4*)(Bs + r * 128 + sw(r, o)) = v;
    }
    __syncthreads();
    int w = tid >> 6, lane = tid & 63;
    int wr = w * 32;
    int m16 = lane & 15, quad = lane >> 4;
    f32x4 acc[2][4] = {};
#pragma unroll
    for (int kk = 0; kk < 128; kk += 32) {
        int ob = (kk >> 3) + quad;
        short8 b[4];
#pragma unroll
        for (int j = 0; j < 4; j++) {
            int r = j * 16 + m16;
            b[j] = *(const short8*)(Bs + r * 128 + sw(r, ob));
        }
#pragma unroll
        for (int i = 0; i < 2; i++) {
            int r = wr + i * 16 + m16;
            short8 a = *(const short8*)(As + r * 128 + sw(r, ob));
#pragma unroll
            for (int j = 0; j < 4; j++)
                acc[i][j] = __builtin_amdgcn_mfma_f32_16x16x32_bf16(a, b[j], acc[i][j], 0, 0, 0);
        }
    }
#pragma unroll
    for (int i = 0; i < 2; i++)
#pragma unroll
        for (int j = 0; j < 4; j++)
#pragma unroll
            for (int reg = 0; reg < 4; reg++) {
                int row = m0 + wr + i * 16 + quad * 4 + reg;
                int col = h * 64 + j * 16 + m16;
                if (row < M) h2[(size_t)row * 576 + col] = f2b(elu(acc[i][j][reg] + b1[col]));
            }
}

// ---------- GEMM2: hl2[M,64](bf16) = h2[M,576](bf16) @ W2t[64,576]^T ----------
__global__ __launch_bounds__(256) void gemm2_k(const unsigned short* __restrict__ A,
                                               const unsigned short* __restrict__ Bt,
                                               unsigned short* __restrict__ Cb, int M) {
    __shared__ __align__(16) unsigned short As[128 * 64];
    __shared__ __align__(16) unsigned short Bs[64 * 64];
    int tid = threadIdx.x;
    int m0 = blockIdx.x * 128;
    int w = tid >> 6, lane = tid & 63;
    int wr = (w >> 1) * 64, wc = (w & 1) * 32;
    int m16 = lane & 15, quad = lane >> 4;
    f32x4 acc[4][2] = {};
    for (int k0 = 0; k0 < 576; k0 += 64) {
        __syncthreads();
        for (int c = tid; c < 1024; c += 256) {  // A: 128 rows x 64k
            int r = c >> 3, o = c & 7;
            int gr = m0 + r;
            uint4 v = make_uint4(0u, 0u, 0u, 0u);
            if (gr < M) v = *(const uint4*)(A + (size_t)gr * 576 + k0 + o * 8);
            *(uint4*)(As + r * 64 + sw(r, o)) = v;
        }
        for (int c = tid; c < 512; c += 256) {   // B: 64 cols x 64k
            int r = c >> 3, o = c & 7;
            uint4 v = *(const uint4*)(Bt + (size_t)r * 576 + k0 + o * 8);
            *(uint4*)(Bs + r * 64 + sw(r, o)) = v;
        }
        __syncthreads();
#pragma unroll
        for (int kk = 0; kk < 64; kk += 32) {
            int ob = (kk >> 3) + quad;
            short8 b[2];
#pragma unroll
            for (int j = 0; j < 2; j++) {
                int r = wc + j * 16 + m16;
                b[j] = *(const short8*)(Bs + r * 64 + sw(r, ob));
            }
#pragma unroll
            for (int i = 0; i < 4; i++) {
                int r = wr + i * 16 + m16;
                short8 a = *(const short8*)(As + r * 64 + sw(r, ob));
#pragma unroll
                for (int j = 0; j < 2; j++)
                    acc[i][j] = __builtin_amdgcn_mfma_f32_16x16x32_bf16(a, b[j], acc[i][j], 0, 0, 0);
            }
        }
    }
#pragma unroll
    for (int i = 0; i < 4; i++)
#pragma unroll
        for (int j = 0; j < 2; j++)
#pragma unroll
            for (int reg = 0; reg < 4; reg++) {
                int row = m0 + wr + i * 16 + quad * 4 + reg;
                int col = wc + j * 16 + m16;
                if (row < M) Cb[(size_t)row * 64 + col] = f2b(acc[i][j][reg]);
            }
}

// ---------- layer2 attn logits (direct dot with a2s/a2d) ----------
__global__ void attn2_k(const unsigned short* __restrict__ hl, const float* __restrict__ aw_s,
                        const float* __restrict__ aw_d, float* __restrict__ als,
                        float* __restrict__ ald, int N) {
    int t = blockIdx.x * blockDim.x + threadIdx.x;
    if (t >= N) return;
    const unsigned short* row = hl + (size_t)t * 64;
    float s_ = 0.f, d_ = 0.f;
#pragma unroll
    for (int c = 0; c < 64; c += 2) {
        unsigned v = *(const unsigned*)(row + c);
        float f0 = blo(v), f1 = bhi(v);
        s_ += f0 * aw_s[c] + f1 * aw_s[c + 1];
        d_ += f0 * aw_d[c] + f1 * aw_d[c + 1];
    }
    als[t] = s_;
    ald[t] = d_;
}

// ---------- layer2 aggregate + normalize + bias + elu -> out2 fp32 ----------
__global__ __launch_bounds__(64) void agg2_k(const unsigned short* __restrict__ hl2,
                                             const float* __restrict__ ex2,
                                             const float* __restrict__ b2,
                                             const int* __restrict__ offs,
                                             const int2* __restrict__ csr,
                                             float* __restrict__ out2, int N) {
    int n = blockIdx.x;
    int t = threadIdx.x;
    if (t >= 32) return;
    int p0 = offs[n], p1 = offs[n + 1];
    float a0 = 0.f, a1 = 0.f, ssum = 0.f;
    for (int p = p0; p < p1; p++) {
        int2 es = csr[p];
        float xv = ex2[es.x];
        unsigned v = *(const unsigned*)(hl2 + (size_t)es.y * 64 + 2 * t);
        ssum += xv;
        a0 += xv * blo(v);
        a1 += xv * bhi(v);
    }
    float inv = 1.f / (ssum + 1e-16f);
    float v0 = elu(a0 * inv + b2[2 * t]);
    float v1 = elu(a1 * inv + b2[2 * t + 1]);
    *(float2*)(out2 + (size_t)n * 64 + 2 * t) = make_float2(v0, v1);
}

// ---------- column reduce ----------
__global__ __launch_bounds__(64) void colred_k(const float* __restrict__ out2,
                                               float* __restrict__ gsum, int N) {
    int c = threadIdx.x;
    int n0 = blockIdx.x * 256;
    int n1 = min(n0 + 256, N);
    float acc = 0.f;
    for (int n = n0; n < n1; n++) acc += out2[(size_t)n * 64 + c];
    atomicAdd(&gsum[c], acc);
}

// ---------- final linear ----------
__global__ __launch_bounds__(256) void final_k(const float* __restrict__ gsum,
                                               const float* __restrict__ fcw,
                                               const float* __restrict__ fcb,
                                               float* __restrict__ out, int N) {
    __shared__ float g[64];
    int t = threadIdx.x;
    if (t < 64) g[t] = gsum[t] / (float)N;
    __syncthreads();
    if (t < 200) {
        float acc = fcb[t];
#pragma unroll
        for (int c = 0; c < 64; c++) acc += g[c] * fcw[c * 200 + t];
        out[t] = acc;
    }
}

extern "C" void kernel_launch(void* const* d_in, const int* in_sizes, int n_in,
                              void* d_out, int out_size, void* d_ws, size_t ws_size,
                              hipStream_t stream) {
    const int* x = (const int*)d_in[0];
    const int* ei = (const int*)d_in[1];
    const int* et = (const int*)d_in[2];
    const float* ent_emb = (const float*)d_in[3];
    const float* rel_emb = (const float*)d_in[4];
    const float* W1 = (const float*)d_in[5];
    const float* a1s = (const float*)d_in[6];
    const float* a1d = (const float*)d_in[7];
    const float* b1 = (const float*)d_in[8];
    const float* W2 = (const float*)d_in[9];
    const float* a2s = (const float*)d_in[10];
    const float* a2d = (const float*)d_in[11];
    const float* b2 = (const float*)d_in[12];
    const float* fcw = (const float*)d_in[13];
    const float* fcb = (const float*)d_in[14];
    float* out = (float*)d_out;

    int N = in_sizes[0];
    int E = in_sizes[1] / 2;
    int Etot = E + N;

    char* p = (char*)d_ws;
    auto alloc = [&](size_t bytes) -> char* {
        char* r = p;
        p += (bytes + 255) & ~(size_t)255;
        return r;
    };
    unsigned short* h1b = (unsigned short*)alloc((size_t)N * 128 * 2);
    float* ws1 = (float*)alloc(1024 * 4);
    float* wd1 = (float*)alloc(1024 * 4);
    // W1t[n][k] = W1[k][n] bf16, built below in a tiny kernel-free way: reuse prep? -> own pass
    unsigned short* W1t = (unsigned short*)alloc((size_t)512 * 128 * 2);
    unsigned short* W2t = (unsigned short*)alloc((size_t)64 * 576 * 2);
    float* als1 = (float*)alloc((size_t)N * 8 * 4);
    float* ald1 = (float*)alloc((size_t)N * 8 * 4);
    float* ex1  = (float*)alloc((size_t)Etot * 8 * 4);
    unsigned* Gu = (unsigned*)alloc((size_t)N * 512 * 4);   // G bf16 [N][8][128]
    unsigned short* h2  = (unsigned short*)alloc((size_t)N * 576 * 2);
    unsigned short* hl2 = (unsigned short*)alloc((size_t)N * 64 * 2);
    float* als2 = (float*)alloc((size_t)N * 4);
    float* ald2 = (float*)alloc((size_t)N * 4);
    float* ex2  = (float*)alloc((size_t)Etot * 4);
    float* out2 = (float*)alloc((size_t)N * 64 * 4);
    float* gsum = (float*)alloc(64 * 4);
    int* deg    = (int*)alloc((size_t)N * 4);
    int* offs   = (int*)alloc((size_t)(N + 1) * 4);
    int* cursor = (int*)alloc((size_t)N * 4);
    int2* csr   = (int2*)alloc((size_t)Etot * 8);

    int tb = 256;
    prep_k<<<(N * 128 + tb - 1) / tb, tb, 0, stream>>>(x, et, ent_emb, rel_emb, W1, W2,
                                                       a1s, a1d, h1b, ws1, wd1, W2t,
                                                       deg, cursor, gsum, N);
    // W1 transpose to bf16 (small helper via lambda-kernel pattern: reuse prep grid? do inline)
    {
        // W1t[n][k] = W1[k][n]; 512*128 = 65536 elems
        struct L {
            static __global__ void k(const float* __restrict__ W1, unsigned short* __restrict__ W1t) {
                int t = blockIdx.x * blockDim.x + threadIdx.x;
                if (t < 512 * 128) {
                    int n = t >> 7, kk = t & 127;
                    W1t[t] = f2b(W1[(size_t)kk * 512 + n]);
                }
            }
        };
        hipLaunchKernelGGL(L::k, dim3((512 * 128 + 255) / 256), dim3(256), 0, stream, W1, W1t);
    }
    attn1_k<<<(N * 8 + tb - 1) / tb, tb, 0, stream>>>((const unsigned*)h1b, ws1, wd1, als1, ald1, N);
    edge_k<8><<<(Etot + tb - 1) / tb, tb, 0, stream>>>(ei, E, N, als1, ald1, ex1, deg);
    scan_k<<<1, 1024, 0, stream>>>(deg, offs, N, Etot);
    fill_k<<<(Etot + tb - 1) / tb, tb, 0, stream>>>(ei, E, N, offs, cursor, csr);
    aggG_k<<<N, 64, 0, stream>>>((const unsigned*)h1b, ex1, offs, csr, Gu, (unsigned*)h2, N);
    gemmG_k<<<dim3((N + 127) / 128, 8), 256, 0, stream>>>((const unsigned short*)Gu, W1t, b1, h2, N);
    gemm2_k<<<(N + 127) / 128, 256, 0, stream>>>(h2, W2t, hl2, N);
    attn2_k<<<(N + tb - 1) / tb, tb, 0, stream>>>(hl2, a2s, a2d, als2, ald2, N);
    edge_k<1><<<(Etot + tb - 1) / tb, tb, 0, stream>>>(ei, E, N, als2, ald2, ex2, nullptr);
    agg2_k<<<N, 64, 0, stream>>>(hl2, ex2, b2, offs, csr, out2, N);
    colred_k<<<(N + 255) / 256, 64, 0, stream>>>(out2, gsum, N);
    final_k<<<1, 256, 0, stream>>>(gsum, fcw, fcb, out, N);
}

// Round 4
// 331.687 us; speedup vs baseline: 2.3417x; 1.1520x over previous
//
#include <hip/hip_runtime.h>
#include <math.h>

#define NEG_SLOPE 0.2f

typedef __attribute__((ext_vector_type(8))) short short8;   // 8 bf16 (4 VGPRs)
typedef __attribute__((ext_vector_type(4))) float f32x4;

// ---------- helpers ----------
__device__ __forceinline__ float lrelu(float v) { return v > 0.f ? v : NEG_SLOPE * v; }
__device__ __forceinline__ float elu(float v) { return v > 0.f ? v : (__expf(v) - 1.f); }
__device__ __forceinline__ unsigned short f2b(float f) {   // fp32 -> bf16 RNE
    unsigned u = __float_as_uint(f);
    return (unsigned short)((u + 0x7FFFu + ((u >> 16) & 1u)) >> 16);
}
__device__ __forceinline__ float blo(unsigned v) { return __uint_as_float(v << 16); }
__device__ __forceinline__ float bhi(unsigned v) { return __uint_as_float(v & 0xFFFF0000u); }
__device__ __forceinline__ unsigned packb(float a, float b) {
    return ((unsigned)f2b(b) << 16) | (unsigned)f2b(a);
}
// LDS xor-swizzle: 16B-chunk o within row r
__device__ __forceinline__ int sw(int r, int o) { return (o ^ (r & 7)) << 3; }

// ---------- prep: h1(bf16), ws1/wd1, W1t, W2t, degree count ----------
__global__ void prep_k(const int* __restrict__ x, const int* __restrict__ et,
                       const int* __restrict__ ei,
                       const float* __restrict__ ent_emb, const float* __restrict__ rel_emb,
                       const float* __restrict__ W1, const float* __restrict__ W2,
                       const float* __restrict__ a1s, const float* __restrict__ a1d,
                       unsigned short* __restrict__ h1b, float* __restrict__ ws1,
                       float* __restrict__ wd1, unsigned short* __restrict__ W1t,
                       unsigned short* __restrict__ W2t, int* __restrict__ deg,
                       int N, int E) {
    int t = blockIdx.x * blockDim.x + threadIdx.x;
    if (t < N * 128) {
        int n = t >> 7, j = t & 127;
        float v = (j < 64) ? ent_emb[(size_t)x[n] * 64 + j]
                           : rel_emb[(size_t)et[n] * 64 + (j - 64)];
        h1b[t] = f2b(v);
    }
    if (t < 1024) {  // ws1[k*8+h] = sum_c W1[k][h*64+c]*a1s[h][c]
        int k = t >> 3, h = t & 7;
        float s_ = 0.f, d_ = 0.f;
        const float* wr = W1 + (size_t)k * 512 + h * 64;
#pragma unroll 16
        for (int c = 0; c < 64; c++) {
            s_ += wr[c] * a1s[h * 64 + c];
            d_ += wr[c] * a1d[h * 64 + c];
        }
        ws1[t] = s_;
        wd1[t] = d_;
    }
    if (t < 512 * 128) {  // W1t[n][k] = W1[k][n]
        int n = t >> 7, kk = t & 127;
        W1t[t] = f2b(W1[(size_t)kk * 512 + n]);
    }
    if (t < 64 * 576) {   // W2t[n][k] = W2[k][n]
        int n = t / 576, k = t % 576;
        W2t[t] = f2b(W2[(size_t)k * 64 + n]);
    }
    if (t < E + N) {      // degree (incl self-loop); deg[] pre-zeroed by memset
        int dst = t < E ? ei[E + t] : t - E;
        atomicAdd(&deg[dst], 1);
    }
}

// ---------- layer1 attn logits: als/ald[n,h] = h1[n] . ws1[:,h] ----------
__global__ void attn1_k(const unsigned* __restrict__ h1u, const float* __restrict__ ws1,
                        const float* __restrict__ wd1, float* __restrict__ als,
                        float* __restrict__ ald, int N) {
    int t = blockIdx.x * blockDim.x + threadIdx.x;
    if (t >= N * 8) return;
    int n = t >> 3, h = t & 7;
    float s_ = 0.f, d_ = 0.f;
#pragma unroll 8
    for (int kk = 0; kk < 64; kk++) {
        unsigned v = h1u[(size_t)n * 64 + kk];
        float f0 = blo(v), f1 = bhi(v);
        s_ += f0 * ws1[(2 * kk) * 8 + h] + f1 * ws1[(2 * kk + 1) * 8 + h];
        d_ += f0 * wd1[(2 * kk) * 8 + h] + f1 * wd1[(2 * kk + 1) * 8 + h];
    }
    als[t] = s_;
    ald[t] = d_;
}

// ---------- single-block scan of degrees -> exclusive offsets ----------
__global__ __launch_bounds__(1024) void scan_k(const int* __restrict__ deg,
                                               int* __restrict__ offs, int N, int Etot) {
    __shared__ int part[1024];
    int t = threadIdx.x;
    const int CH = (N + 1023) / 1024;
    int base = t * CH;
    int sum = 0;
    for (int i = 0; i < CH; i++) {
        int idx = base + i;
        if (idx < N) sum += deg[idx];
    }
    part[t] = sum;
    __syncthreads();
    for (int off = 1; off < 1024; off <<= 1) {
        int v = (t >= off) ? part[t - off] : 0;
        __syncthreads();
        part[t] += v;
        __syncthreads();
    }
    int run = (t == 0) ? 0 : part[t - 1];
    for (int i = 0; i < CH; i++) {
        int idx = base + i;
        if (idx < N) { offs[idx] = run; run += deg[idx]; }
    }
    if (t == 0) offs[N] = Etot;
}

// ---------- CSR fill (src only) ----------
__global__ void fill_k(const int* __restrict__ ei, int E, int N,
                       const int* __restrict__ offs, int* __restrict__ cursor,
                       int* __restrict__ csr) {
    int e = blockIdx.x * blockDim.x + threadIdx.x;
    if (e >= E + N) return;
    int src = e < E ? ei[e] : e - E;
    int dst = e < E ? ei[E + e] : e - E;
    int pos = offs[dst] + atomicAdd(&cursor[dst], 1);
    csr[pos] = src;
}

// ---------- aggG: G[n][h][k] = softmax-weighted sum of h1[src][k]; exp inline ----------
__global__ __launch_bounds__(64) void aggG_k(const unsigned* __restrict__ h1u,
                                             const float* __restrict__ als1,
                                             const float* __restrict__ ald1,
                                             const int* __restrict__ offs,
                                             const int* __restrict__ csr,
                                             unsigned* __restrict__ Gu,
                                             unsigned* __restrict__ h2u, int N) {
    int n = blockIdx.x;
    int t = threadIdx.x;
    int p0 = offs[n], p1 = offs[n + 1];
    float4 d0 = *(const float4*)(ald1 + (size_t)n * 8);
    float4 d1 = *(const float4*)(ald1 + (size_t)n * 8 + 4);
    float dl[8] = {d0.x, d0.y, d0.z, d0.w, d1.x, d1.y, d1.z, d1.w};
    float a0[8] = {}, a1[8] = {}, ssum[8] = {};
    for (int p = p0; p < p1; p++) {
        int src = csr[p];
        float4 s0 = *(const float4*)(als1 + (size_t)src * 8);
        float4 s1 = *(const float4*)(als1 + (size_t)src * 8 + 4);
        float sl[8] = {s0.x, s0.y, s0.z, s0.w, s1.x, s1.y, s1.z, s1.w};
        unsigned hv = h1u[(size_t)src * 64 + t];
        float f0 = blo(hv), f1 = bhi(hv);
#pragma unroll
        for (int h = 0; h < 8; h++) {
            float xv = __expf(lrelu(sl[h] + dl[h]));
            a0[h] += xv * f0;
            a1[h] += xv * f1;
            ssum[h] += xv;
        }
    }
#pragma unroll
    for (int h = 0; h < 8; h++) {
        float inv = 1.f / (ssum[h] + 1e-16f);
        Gu[(size_t)n * 512 + h * 64 + t] = packb(a0[h] * inv, a1[h] * inv);
    }
    if (t < 32)  // ent tail: h2 cols 512..575 = h1 cols 0..63
        h2u[(size_t)n * 288 + 256 + t] = h1u[(size_t)n * 64 + t];
}

// ---------- gemmG: h2[n][h*64+j] = elu(G[n][h] . W1t[h*64+j] + b1)  per-head GEMM ----------
__global__ __launch_bounds__(256) void gemmG_k(const unsigned short* __restrict__ Gb,
                                               const unsigned short* __restrict__ W1t,
                                               const float* __restrict__ b1,
                                               unsigned short* __restrict__ h2, int M) {
    __shared__ __align__(16) unsigned short As[128 * 128];
    __shared__ __align__(16) unsigned short Bs[64 * 128];
    int tid = threadIdx.x;
    int m0 = blockIdx.x * 128, h = blockIdx.y;
    for (int c = tid; c < 2048; c += 256) {  // A: 128 node-rows x 128 k
        int r = c >> 4, o = c & 15;
        int gr = m0 + r;
        uint4 v = make_uint4(0u, 0u, 0u, 0u);
        if (gr < M) v = *(const uint4*)(Gb + (size_t)gr * 1024 + h * 128 + o * 8);
        *(uint4*)(As + r * 128 + sw(r, o)) = v;
    }
    for (int c = tid; c < 1024; c += 256) {  // B: 64 col-rows x 128 k
        int r = c >> 4, o = c & 15;
        uint4 v = *(const uint4*)(W1t + (size_t)(h * 64 + r) * 128 + o * 8);
        *(uint4*)(Bs + r * 128 + sw(r, o)) = v;
    }
    __syncthreads();
    int w = tid >> 6, lane = tid & 63;
    int wr = w * 32;
    int m16 = lane & 15, quad = lane >> 4;
    f32x4 acc[2][4] = {};
#pragma unroll
    for (int kk = 0; kk < 128; kk += 32) {
        int ob = (kk >> 3) + quad;
        short8 b[4];
#pragma unroll
        for (int j = 0; j < 4; j++) {
            int r = j * 16 + m16;
            b[j] = *(const short8*)(Bs + r * 128 + sw(r, ob));
        }
#pragma unroll
        for (int i = 0; i < 2; i++) {
            int r = wr + i * 16 + m16;
            short8 a = *(const short8*)(As + r * 128 + sw(r, ob));
#pragma unroll
            for (int j = 0; j < 4; j++)
                acc[i][j] = __builtin_amdgcn_mfma_f32_16x16x32_bf16(a, b[j], acc[i][j], 0, 0, 0);
        }
    }
#pragma unroll
    for (int i = 0; i < 2; i++)
#pragma unroll
        for (int j = 0; j < 4; j++)
#pragma unroll
            for (int reg = 0; reg < 4; reg++) {
                int row = m0 + wr + i * 16 + quad * 4 + reg;
                int col = h * 64 + j * 16 + m16;
                if (row < M) h2[(size_t)row * 576 + col] = f2b(elu(acc[i][j][reg] + b1[col]));
            }
}

// ---------- GEMM2: hl2[M,64](bf16) = h2[M,576](bf16) @ W2t[64,576]^T ----------
__global__ __launch_bounds__(256) void gemm2_k(const unsigned short* __restrict__ A,
                                               const unsigned short* __restrict__ Bt,
                                               unsigned short* __restrict__ Cb, int M) {
    __shared__ __align__(16) unsigned short As[128 * 64];
    __shared__ __align__(16) unsigned short Bs[64 * 64];
    int tid = threadIdx.x;
    int m0 = blockIdx.x * 128;
    int w = tid >> 6, lane = tid & 63;
    int wr = (w >> 1) * 64, wc = (w & 1) * 32;
    int m16 = lane & 15, quad = lane >> 4;
    f32x4 acc[4][2] = {};
    for (int k0 = 0; k0 < 576; k0 += 64) {
        __syncthreads();
        for (int c = tid; c < 1024; c += 256) {  // A: 128 rows x 64k
            int r = c >> 3, o = c & 7;
            int gr = m0 + r;
            uint4 v = make_uint4(0u, 0u, 0u, 0u);
            if (gr < M) v = *(const uint4*)(A + (size_t)gr * 576 + k0 + o * 8);
            *(uint4*)(As + r * 64 + sw(r, o)) = v;
        }
        for (int c = tid; c < 512; c += 256) {   // B: 64 cols x 64k
            int r = c >> 3, o = c & 7;
            uint4 v = *(const uint4*)(Bt + (size_t)r * 576 + k0 + o * 8);
            *(uint4*)(Bs + r * 64 + sw(r, o)) = v;
        }
        __syncthreads();
#pragma unroll
        for (int kk = 0; kk < 64; kk += 32) {
            int ob = (kk >> 3) + quad;
            short8 b[2];
#pragma unroll
            for (int j = 0; j < 2; j++) {
                int r = wc + j * 16 + m16;
                b[j] = *(const short8*)(Bs + r * 64 + sw(r, ob));
            }
#pragma unroll
            for (int i = 0; i < 4; i++) {
                int r = wr + i * 16 + m16;
                short8 a = *(const short8*)(As + r * 64 + sw(r, ob));
#pragma unroll
                for (int j = 0; j < 2; j++)
                    acc[i][j] = __builtin_amdgcn_mfma_f32_16x16x32_bf16(a, b[j], acc[i][j], 0, 0, 0);
            }
        }
    }
#pragma unroll
    for (int i = 0; i < 4; i++)
#pragma unroll
        for (int j = 0; j < 2; j++)
#pragma unroll
            for (int reg = 0; reg < 4; reg++) {
                int row = m0 + wr + i * 16 + quad * 4 + reg;
                int col = wc + j * 16 + m16;
                if (row < M) Cb[(size_t)row * 64 + col] = f2b(acc[i][j][reg]);
            }
}

// ---------- layer2 attn logits ----------
__global__ void attn2_k(const unsigned short* __restrict__ hl, const float* __restrict__ aw_s,
                        const float* __restrict__ aw_d, float* __restrict__ als,
                        float* __restrict__ ald, int N) {
    int t = blockIdx.x * blockDim.x + threadIdx.x;
    if (t >= N) return;
    const unsigned short* row = hl + (size_t)t * 64;
    float s_ = 0.f, d_ = 0.f;
#pragma unroll
    for (int c = 0; c < 64; c += 2) {
        unsigned v = *(const unsigned*)(row + c);
        float f0 = blo(v), f1 = bhi(v);
        s_ += f0 * aw_s[c] + f1 * aw_s[c + 1];
        d_ += f0 * aw_d[c] + f1 * aw_d[c + 1];
    }
    als[t] = s_;
    ald[t] = d_;
}

// ---------- layer2 aggregate (exp inline) + normalize + bias + elu -> out2 fp32 ----------
// 256 threads = 8 node-slots x 32 lanes
__global__ __launch_bounds__(256) void agg2_k(const unsigned short* __restrict__ hl2,
                                              const float* __restrict__ als2,
                                              const float* __restrict__ ald2,
                                              const float* __restrict__ b2,
                                              const int* __restrict__ offs,
                                              const int* __restrict__ csr,
                                              float* __restrict__ out2, int N) {
    int slot = threadIdx.x >> 5, l = threadIdx.x & 31;
    int n = blockIdx.x * 8 + slot;
    if (n >= N) return;
    int p0 = offs[n], p1 = offs[n + 1];
    float dl = ald2[n];
    float a0 = 0.f, a1 = 0.f, ssum = 0.f;
    for (int p = p0; p < p1; p++) {
        int src = csr[p];
        float xv = __expf(lrelu(als2[src] + dl));
        unsigned v = *(const unsigned*)(hl2 + (size_t)src * 64 + 2 * l);
        ssum += xv;
        a0 += xv * blo(v);
        a1 += xv * bhi(v);
    }
    float inv = 1.f / (ssum + 1e-16f);
    float v0 = elu(a0 * inv + b2[2 * l]);
    float v1 = elu(a1 * inv + b2[2 * l + 1]);
    *(float2*)(out2 + (size_t)n * 64 + 2 * l) = make_float2(v0, v1);
}

// ---------- column reduce: 256 threads = 4 row-groups x 64 cols ----------
__global__ __launch_bounds__(256) void colred_k(const float* __restrict__ out2,
                                                float* __restrict__ gsum, int N) {
    __shared__ float red[256];
    int t = threadIdx.x;
    int c = t & 63, rg = t >> 6;
    int n1 = min(blockIdx.x * 256 + 256, N);
    float acc = 0.f;
    for (int n = blockIdx.x * 256 + rg; n < n1; n += 4)
        acc += out2[(size_t)n * 64 + c];
    red[t] = acc;
    __syncthreads();
    if (t < 64) atomicAdd(&gsum[c], red[c] + red[c + 64] + red[c + 128] + red[c + 192]);
}

// ---------- final linear ----------
__global__ __launch_bounds__(256) void final_k(const float* __restrict__ gsum,
                                               const float* __restrict__ fcw,
                                               const float* __restrict__ fcb,
                                               float* __restrict__ out, int N) {
    __shared__ float g[64];
    int t = threadIdx.x;
    if (t < 64) g[t] = gsum[t] / (float)N;
    __syncthreads();
    if (t < 200) {
        float acc = fcb[t];
#pragma unroll
        for (int c = 0; c < 64; c++) acc += g[c] * fcw[c * 200 + t];
        out[t] = acc;
    }
}

extern "C" void kernel_launch(void* const* d_in, const int* in_sizes, int n_in,
                              void* d_out, int out_size, void* d_ws, size_t ws_size,
                              hipStream_t stream) {
    const int* x = (const int*)d_in[0];
    const int* ei = (const int*)d_in[1];
    const int* et = (const int*)d_in[2];
    const float* ent_emb = (const float*)d_in[3];
    const float* rel_emb = (const float*)d_in[4];
    const float* W1 = (const float*)d_in[5];
    const float* a1s = (const float*)d_in[6];
    const float* a1d = (const float*)d_in[7];
    const float* b1 = (const float*)d_in[8];
    const float* W2 = (const float*)d_in[9];
    const float* a2s = (const float*)d_in[10];
    const float* a2d = (const float*)d_in[11];
    const float* b2 = (const float*)d_in[12];
    const float* fcw = (const float*)d_in[13];
    const float* fcb = (const float*)d_in[14];
    float* out = (float*)d_out;

    int N = in_sizes[0];
    int E = in_sizes[1] / 2;
    int Etot = E + N;

    char* p = (char*)d_ws;
    auto alloc = [&](size_t bytes) -> char* {
        char* r = p;
        p += (bytes + 255) & ~(size_t)255;
        return r;
    };
    unsigned short* h1b = (unsigned short*)alloc((size_t)N * 128 * 2);
    float* ws1 = (float*)alloc(1024 * 4);
    float* wd1 = (float*)alloc(1024 * 4);
    unsigned short* W1t = (unsigned short*)alloc((size_t)512 * 128 * 2);
    unsigned short* W2t = (unsigned short*)alloc((size_t)64 * 576 * 2);
    float* als1 = (float*)alloc((size_t)N * 8 * 4);
    float* ald1 = (float*)alloc((size_t)N * 8 * 4);
    unsigned* Gu = (unsigned*)alloc((size_t)N * 512 * 4);   // G bf16 [N][8][128]
    unsigned short* h2  = (unsigned short*)alloc((size_t)N * 576 * 2);
    unsigned short* hl2 = (unsigned short*)alloc((size_t)N * 64 * 2);
    float* als2 = (float*)alloc((size_t)N * 4);
    float* ald2 = (float*)alloc((size_t)N * 4);
    float* out2 = (float*)alloc((size_t)N * 64 * 4);
    int* offs   = (int*)alloc((size_t)(N + 1) * 4);
    int* csr    = (int*)alloc((size_t)Etot * 4);
    // zero-init region: deg, cursor, gsum contiguous
    char* z0 = p;
    int* deg    = (int*)alloc((size_t)N * 4);
    int* cursor = (int*)alloc((size_t)N * 4);
    float* gsum = (float*)alloc(64 * 4);
    size_t zbytes = (size_t)(p - z0);

    int tb = 256;
    hipMemsetAsync(z0, 0, zbytes, stream);
    prep_k<<<(N * 128 + tb - 1) / tb, tb, 0, stream>>>(x, et, ei, ent_emb, rel_emb, W1, W2,
                                                       a1s, a1d, h1b, ws1, wd1, W1t, W2t,
                                                       deg, N, E);
    attn1_k<<<(N * 8 + tb - 1) / tb, tb, 0, stream>>>((const unsigned*)h1b, ws1, wd1, als1, ald1, N);
    scan_k<<<1, 1024, 0, stream>>>(deg, offs, N, Etot);
    fill_k<<<(Etot + tb - 1) / tb, tb, 0, stream>>>(ei, E, N, offs, cursor, csr);
    aggG_k<<<N, 64, 0, stream>>>((const unsigned*)h1b, als1, ald1, offs, csr, Gu, (unsigned*)h2, N);
    gemmG_k<<<dim3((N + 127) / 128, 8), 256, 0, stream>>>((const unsigned short*)Gu, W1t, b1, h2, N);
    gemm2_k<<<(N + 127) / 128, 256, 0, stream>>>(h2, W2t, hl2, N);
    attn2_k<<<(N + tb - 1) / tb, tb, 0, stream>>>(hl2, a2s, a2d, als2, ald2, N);
    agg2_k<<<(N + 7) / 8, 256, 0, stream>>>(hl2, als2, ald2, b2, offs, csr, out2, N);
    colred_k<<<(N + 255) / 256, 256, 0, stream>>>(out2, gsum, N);
    final_k<<<1, 256, 0, stream>>>(gsum, fcw, fcb, out, N);
}

// Round 5
// 294.661 us; speedup vs baseline: 2.6360x; 1.1257x over previous
//
#include <hip/hip_runtime.h>
#include <math.h>

#define NEG_SLOPE 0.2f

typedef __attribute__((ext_vector_type(8))) short short8;   // 8 bf16 (4 VGPRs)
typedef __attribute__((ext_vector_type(4))) float f32x4;

// ---------- helpers ----------
__device__ __forceinline__ float lrelu(float v) { return v > 0.f ? v : NEG_SLOPE * v; }
__device__ __forceinline__ float elu(float v) { return v > 0.f ? v : (__expf(v) - 1.f); }
__device__ __forceinline__ unsigned short f2b(float f) {   // fp32 -> bf16 RNE
    unsigned u = __float_as_uint(f);
    return (unsigned short)((u + 0x7FFFu + ((u >> 16) & 1u)) >> 16);
}
__device__ __forceinline__ float blo(unsigned v) { return __uint_as_float(v << 16); }
__device__ __forceinline__ float bhi(unsigned v) { return __uint_as_float(v & 0xFFFF0000u); }
__device__ __forceinline__ unsigned packb(float a, float b) {
    return ((unsigned)f2b(b) << 16) | (unsigned)f2b(a);
}
// LDS xor-swizzle: 16B-chunk o within row r
__device__ __forceinline__ int sw(int r, int o) { return (o ^ (r & 7)) << 3; }

// ---------- prep: h1(bf16), wsb[16][128], W1t, W2t, degree count ----------
__global__ void prep_k(const int* __restrict__ x, const int* __restrict__ et,
                       const int* __restrict__ ei,
                       const float* __restrict__ ent_emb, const float* __restrict__ rel_emb,
                       const float* __restrict__ W1, const float* __restrict__ W2,
                       const float* __restrict__ a1s, const float* __restrict__ a1d,
                       unsigned short* __restrict__ h1b, unsigned short* __restrict__ wsb,
                       unsigned short* __restrict__ W1t, unsigned short* __restrict__ W2t,
                       int* __restrict__ deg, int N, int E) {
    int t = blockIdx.x * blockDim.x + threadIdx.x;
    if (t < N * 128) {
        int n = t >> 7, j = t & 127;
        float v = (j < 64) ? ent_emb[(size_t)x[n] * 64 + j]
                           : rel_emb[(size_t)et[n] * 64 + (j - 64)];
        h1b[t] = f2b(v);
    }
    if (t < 2048) {  // wsb[hh][k]: hh<8 -> W1.a1s head hh, hh>=8 -> W1.a1d head hh-8
        int hh = t >> 7, k = t & 127;
        int h = hh & 7;
        const float* aw = (hh < 8) ? a1s : a1d;
        const float* wr = W1 + (size_t)k * 512 + h * 64;
        float s_ = 0.f;
#pragma unroll 16
        for (int c = 0; c < 64; c++) s_ += wr[c] * aw[h * 64 + c];
        wsb[t] = f2b(s_);
    }
    if (t < 512 * 128) {  // W1t[n][k] = W1[k][n]
        int n = t >> 7, kk = t & 127;
        W1t[t] = f2b(W1[(size_t)kk * 512 + n]);
    }
    if (t < 64 * 576) {   // W2t[n][k] = W2[k][n]
        int n = t / 576, k = t % 576;
        W2t[t] = f2b(W2[(size_t)k * 64 + n]);
    }
    if (t < E + N) {      // degree (incl self-loop); deg[] pre-zeroed by memset
        int dst = t < E ? ei[E + t] : t - E;
        atomicAdd(&deg[dst], 1);
    }
}

// ---------- attn1 (MFMA): [als|ald][N,16] = h1[N,128] @ wsb[16,128]^T ----------
__global__ __launch_bounds__(256) void attn1_k(const unsigned short* __restrict__ A,
                                               const unsigned short* __restrict__ Bt,
                                               float* __restrict__ als, float* __restrict__ ald,
                                               int M) {
    __shared__ __align__(16) unsigned short As[128 * 128];
    __shared__ __align__(16) unsigned short Bs[16 * 128];
    int tid = threadIdx.x;
    int m0 = blockIdx.x * 128;
    for (int c = tid; c < 2048; c += 256) {
        int r = c >> 4, o = c & 15;
        int gr = m0 + r;
        uint4 v = make_uint4(0u, 0u, 0u, 0u);
        if (gr < M) v = *(const uint4*)(A + (size_t)gr * 128 + o * 8);
        *(uint4*)(As + r * 128 + sw(r, o)) = v;
    }
    if (tid < 256) {
        int r = tid >> 4, o = tid & 15;
        uint4 v = *(const uint4*)(Bt + (size_t)r * 128 + o * 8);
        *(uint4*)(Bs + r * 128 + sw(r, o)) = v;
    }
    __syncthreads();
    int w = tid >> 6, lane = tid & 63;
    int wr = w * 32;
    int m16 = lane & 15, quad = lane >> 4;
    f32x4 acc[2] = {};
#pragma unroll
    for (int kk = 0; kk < 128; kk += 32) {
        int ob = (kk >> 3) + quad;
        short8 b = *(const short8*)(Bs + m16 * 128 + sw(m16, ob));
#pragma unroll
        for (int i = 0; i < 2; i++) {
            int r = wr + i * 16 + m16;
            short8 a = *(const short8*)(As + r * 128 + sw(r, ob));
            acc[i] = __builtin_amdgcn_mfma_f32_16x16x32_bf16(a, b, acc[i], 0, 0, 0);
        }
    }
#pragma unroll
    for (int i = 0; i < 2; i++)
#pragma unroll
        for (int reg = 0; reg < 4; reg++) {
            int row = m0 + wr + i * 16 + quad * 4 + reg;
            if (row < M) {
                if (m16 < 8) als[row * 8 + m16] = acc[i][reg];
                else         ald[row * 8 + (m16 - 8)] = acc[i][reg];
            }
        }
}

// ---------- 3-phase parallel scan ----------
__global__ __launch_bounds__(256) void scanA_k(const int* __restrict__ deg,
                                               int* __restrict__ bsum, int N) {
    __shared__ int red[256];
    int t = threadIdx.x;
    int i = blockIdx.x * 256 + t;
    red[t] = (i < N) ? deg[i] : 0;
    __syncthreads();
    for (int off = 128; off > 0; off >>= 1) {
        if (t < off) red[t] += red[t + off];
        __syncthreads();
    }
    if (t == 0) bsum[blockIdx.x] = red[0];
}
__global__ void scanB_k(const int* __restrict__ bsum, int* __restrict__ bbase,
                        int* __restrict__ offs, int NB, int N, int Etot) {
    if (threadIdx.x == 0) {
        int run = 0;
        for (int i = 0; i < NB; i++) { bbase[i] = run; run += bsum[i]; }
        offs[N] = Etot;
    }
}
__global__ __launch_bounds__(256) void scanC_k(const int* __restrict__ deg,
                                               const int* __restrict__ bbase,
                                               int* __restrict__ offs, int N) {
    __shared__ int s[256];
    int t = threadIdx.x;
    int i = blockIdx.x * 256 + t;
    int v = (i < N) ? deg[i] : 0;
    s[t] = v;
    __syncthreads();
    for (int off = 1; off < 256; off <<= 1) {
        int tmp = (t >= off) ? s[t - off] : 0;
        __syncthreads();
        s[t] += tmp;
        __syncthreads();
    }
    if (i < N) offs[i] = bbase[blockIdx.x] + s[t] - v;
}

// ---------- CSR fill (src only) ----------
__global__ void fill_k(const int* __restrict__ ei, int E, int N,
                       const int* __restrict__ offs, int* __restrict__ cursor,
                       int* __restrict__ csr) {
    int e = blockIdx.x * blockDim.x + threadIdx.x;
    if (e >= E + N) return;
    int src = e < E ? ei[e] : e - E;
    int dst = e < E ? ei[E + e] : e - E;
    int pos = offs[dst] + atomicAdd(&cursor[dst], 1);
    csr[pos] = src;
}

// ---------- alpha1: ex1[p][h] (CSR order, unnormalized), inv1[n][h] ----------
__global__ __launch_bounds__(256) void alpha1_k(const float* __restrict__ als1,
                                                const float* __restrict__ ald1,
                                                const int* __restrict__ offs,
                                                const int* __restrict__ csr,
                                                float* __restrict__ ex1,
                                                float* __restrict__ inv1, int N) {
    int slot = threadIdx.x >> 3, h = threadIdx.x & 7;
    int n = blockIdx.x * 32 + slot;
    if (n >= N) return;
    float dl = ald1[n * 8 + h];
    int p0 = offs[n], p1 = offs[n + 1];
    float ssum = 0.f;
    for (int p = p0; p < p1; p++) {
        int src = csr[p];
        float xv = __expf(lrelu(als1[src * 8 + h] + dl));
        ex1[(size_t)p * 8 + h] = xv;
        ssum += xv;
    }
    inv1[n * 8 + h] = 1.f / (ssum + 1e-16f);
}

// ---------- aggG: G[n][h][k] = inv1 * sum_p ex1[p][h] h1[src_p][k]  (bf16) ----------
__global__ __launch_bounds__(64) void aggG_k(const unsigned* __restrict__ h1u,
                                             const float* __restrict__ ex1,
                                             const float* __restrict__ inv1,
                                             const int* __restrict__ offs,
                                             const int* __restrict__ csr,
                                             unsigned* __restrict__ Gu,
                                             unsigned* __restrict__ h2u, int N) {
    int n = blockIdx.x;
    int t = threadIdx.x;
    int p0 = offs[n], p1 = offs[n + 1];
    float a0[8] = {}, a1[8] = {};
    for (int p = p0; p < p1; p++) {
        int src = csr[p];
        float4 e0 = *(const float4*)(ex1 + (size_t)p * 8);
        float4 e1 = *(const float4*)(ex1 + (size_t)p * 8 + 4);
        float ev[8] = {e0.x, e0.y, e0.z, e0.w, e1.x, e1.y, e1.z, e1.w};
        unsigned hv = h1u[(size_t)src * 64 + t];
        float f0 = blo(hv), f1 = bhi(hv);
#pragma unroll
        for (int h = 0; h < 8; h++) {
            a0[h] += ev[h] * f0;
            a1[h] += ev[h] * f1;
        }
    }
    float4 i0 = *(const float4*)(inv1 + (size_t)n * 8);
    float4 i1 = *(const float4*)(inv1 + (size_t)n * 8 + 4);
    float iv[8] = {i0.x, i0.y, i0.z, i0.w, i1.x, i1.y, i1.z, i1.w};
#pragma unroll
    for (int h = 0; h < 8; h++)
        Gu[(size_t)n * 512 + h * 64 + t] = packb(a0[h] * iv[h], a1[h] * iv[h]);
    if (t < 32)  // ent tail: h2 cols 512..575 = h1 cols 0..63
        h2u[(size_t)n * 288 + 256 + t] = h1u[(size_t)n * 64 + t];
}

// ---------- gemmG: h2[n][h*64+j] = elu(G[n][h] . W1t[h*64+j] + b1) ----------
__global__ __launch_bounds__(256) void gemmG_k(const unsigned short* __restrict__ Gb,
                                               const unsigned short* __restrict__ W1t,
                                               const float* __restrict__ b1,
                                               unsigned short* __restrict__ h2, int M) {
    __shared__ __align__(16) unsigned short As[128 * 128];
    __shared__ __align__(16) unsigned short Bs[64 * 128];
    int tid = threadIdx.x;
    int m0 = blockIdx.x * 128, h = blockIdx.y;
    for (int c = tid; c < 2048; c += 256) {
        int r = c >> 4, o = c & 15;
        int gr = m0 + r;
        uint4 v = make_uint4(0u, 0u, 0u, 0u);
        if (gr < M) v = *(const uint4*)(Gb + (size_t)gr * 1024 + h * 128 + o * 8);
        *(uint4*)(As + r * 128 + sw(r, o)) = v;
    }
    for (int c = tid; c < 1024; c += 256) {
        int r = c >> 4, o = c & 15;
        uint4 v = *(const uint4*)(W1t + (size_t)(h * 64 + r) * 128 + o * 8);
        *(uint4*)(Bs + r * 128 + sw(r, o)) = v;
    }
    __syncthreads();
    int w = tid >> 6, lane = tid & 63;
    int wr = w * 32;
    int m16 = lane & 15, quad = lane >> 4;
    f32x4 acc[2][4] = {};
#pragma unroll
    for (int kk = 0; kk < 128; kk += 32) {
        int ob = (kk >> 3) + quad;
        short8 b[4];
#pragma unroll
        for (int j = 0; j < 4; j++) {
            int r = j * 16 + m16;
            b[j] = *(const short8*)(Bs + r * 128 + sw(r, ob));
        }
#pragma unroll
        for (int i = 0; i < 2; i++) {
            int r = wr + i * 16 + m16;
            short8 a = *(const short8*)(As + r * 128 + sw(r, ob));
#pragma unroll
            for (int j = 0; j < 4; j++)
                acc[i][j] = __builtin_amdgcn_mfma_f32_16x16x32_bf16(a, b[j], acc[i][j], 0, 0, 0);
        }
    }
#pragma unroll
    for (int i = 0; i < 2; i++)
#pragma unroll
        for (int j = 0; j < 4; j++)
#pragma unroll
            for (int reg = 0; reg < 4; reg++) {
                int row = m0 + wr + i * 16 + quad * 4 + reg;
                int col = h * 64 + j * 16 + m16;
                if (row < M) h2[(size_t)row * 576 + col] = f2b(elu(acc[i][j][reg] + b1[col]));
            }
}

// ---------- GEMM2: hl2[M,64](bf16) = h2[M,576](bf16) @ W2t[64,576]^T ----------
__global__ __launch_bounds__(256) void gemm2_k(const unsigned short* __restrict__ A,
                                               const unsigned short* __restrict__ Bt,
                                               unsigned short* __restrict__ Cb, int M) {
    __shared__ __align__(16) unsigned short As[128 * 64];
    __shared__ __align__(16) unsigned short Bs[64 * 64];
    int tid = threadIdx.x;
    int m0 = blockIdx.x * 128;
    int w = tid >> 6, lane = tid & 63;
    int wr = (w >> 1) * 64, wc = (w & 1) * 32;
    int m16 = lane & 15, quad = lane >> 4;
    f32x4 acc[4][2] = {};
    for (int k0 = 0; k0 < 576; k0 += 64) {
        __syncthreads();
        for (int c = tid; c < 1024; c += 256) {
            int r = c >> 3, o = c & 7;
            int gr = m0 + r;
            uint4 v = make_uint4(0u, 0u, 0u, 0u);
            if (gr < M) v = *(const uint4*)(A + (size_t)gr * 576 + k0 + o * 8);
            *(uint4*)(As + r * 64 + sw(r, o)) = v;
        }
        for (int c = tid; c < 512; c += 256) {
            int r = c >> 3, o = c & 7;
            uint4 v = *(const uint4*)(Bt + (size_t)r * 576 + k0 + o * 8);
            *(uint4*)(Bs + r * 64 + sw(r, o)) = v;
        }
        __syncthreads();
#pragma unroll
        for (int kk = 0; kk < 64; kk += 32) {
            int ob = (kk >> 3) + quad;
            short8 b[2];
#pragma unroll
            for (int j = 0; j < 2; j++) {
                int r = wc + j * 16 + m16;
                b[j] = *(const short8*)(Bs + r * 64 + sw(r, ob));
            }
#pragma unroll
            for (int i = 0; i < 4; i++) {
                int r = wr + i * 16 + m16;
                short8 a = *(const short8*)(As + r * 64 + sw(r, ob));
#pragma unroll
                for (int j = 0; j < 2; j++)
                    acc[i][j] = __builtin_amdgcn_mfma_f32_16x16x32_bf16(a, b[j], acc[i][j], 0, 0, 0);
            }
        }
    }
#pragma unroll
    for (int i = 0; i < 4; i++)
#pragma unroll
        for (int j = 0; j < 2; j++)
#pragma unroll
            for (int reg = 0; reg < 4; reg++) {
                int row = m0 + wr + i * 16 + quad * 4 + reg;
                int col = wc + j * 16 + m16;
                if (row < M) Cb[(size_t)row * 64 + col] = f2b(acc[i][j][reg]);
            }
}

// ---------- layer2 attn logits ----------
__global__ void attn2_k(const unsigned short* __restrict__ hl, const float* __restrict__ aw_s,
                        const float* __restrict__ aw_d, float* __restrict__ als,
                        float* __restrict__ ald, int N) {
    int t = blockIdx.x * blockDim.x + threadIdx.x;
    if (t >= N) return;
    const unsigned short* row = hl + (size_t)t * 64;
    float s_ = 0.f, d_ = 0.f;
#pragma unroll
    for (int c = 0; c < 64; c += 2) {
        unsigned v = *(const unsigned*)(row + c);
        float f0 = blo(v), f1 = bhi(v);
        s_ += f0 * aw_s[c] + f1 * aw_s[c + 1];
        d_ += f0 * aw_d[c] + f1 * aw_d[c + 1];
    }
    als[t] = s_;
    ald[t] = d_;
}

// ---------- alpha2: ex2[p] (CSR order), inv2[n] ----------
__global__ __launch_bounds__(256) void alpha2_k(const float* __restrict__ als2,
                                                const float* __restrict__ ald2,
                                                const int* __restrict__ offs,
                                                const int* __restrict__ csr,
                                                float* __restrict__ ex2,
                                                float* __restrict__ inv2, int N) {
    int n = blockIdx.x * blockDim.x + threadIdx.x;
    if (n >= N) return;
    float dl = ald2[n];
    int p0 = offs[n], p1 = offs[n + 1];
    float ssum = 0.f;
    for (int p = p0; p < p1; p++) {
        float xv = __expf(lrelu(als2[csr[p]] + dl));
        ex2[p] = xv;
        ssum += xv;
    }
    inv2[n] = 1.f / (ssum + 1e-16f);
}

// ---------- layer2 aggregate -> out2 fp32; 8 node-slots x 32 lanes ----------
__global__ __launch_bounds__(256) void agg2_k(const unsigned short* __restrict__ hl2,
                                              const float* __restrict__ ex2,
                                              const float* __restrict__ inv2,
                                              const float* __restrict__ b2,
                                              const int* __restrict__ offs,
                                              const int* __restrict__ csr,
                                              float* __restrict__ out2, int N) {
    int slot = threadIdx.x >> 5, l = threadIdx.x & 31;
    int n = blockIdx.x * 8 + slot;
    if (n >= N) return;
    int p0 = offs[n], p1 = offs[n + 1];
    float a0 = 0.f, a1 = 0.f;
    for (int p = p0; p < p1; p++) {
        int src = csr[p];
        float xv = ex2[p];
        unsigned v = *(const unsigned*)(hl2 + (size_t)src * 64 + 2 * l);
        a0 += xv * blo(v);
        a1 += xv * bhi(v);
    }
    float inv = inv2[n];
    float v0 = elu(a0 * inv + b2[2 * l]);
    float v1 = elu(a1 * inv + b2[2 * l + 1]);
    *(float2*)(out2 + (size_t)n * 64 + 2 * l) = make_float2(v0, v1);
}

// ---------- column reduce: 256 threads = 4 row-groups x 64 cols ----------
__global__ __launch_bounds__(256) void colred_k(const float* __restrict__ out2,
                                                float* __restrict__ gsum, int N) {
    __shared__ float red[256];
    int t = threadIdx.x;
    int c = t & 63, rg = t >> 6;
    int n1 = min(blockIdx.x * 256 + 256, N);
    float acc = 0.f;
    for (int n = blockIdx.x * 256 + rg; n < n1; n += 4)
        acc += out2[(size_t)n * 64 + c];
    red[t] = acc;
    __syncthreads();
    if (t < 64) atomicAdd(&gsum[c], red[c] + red[c + 64] + red[c + 128] + red[c + 192]);
}

// ---------- final linear ----------
__global__ __launch_bounds__(256) void final_k(const float* __restrict__ gsum,
                                               const float* __restrict__ fcw,
                                               const float* __restrict__ fcb,
                                               float* __restrict__ out, int N) {
    __shared__ float g[64];
    int t = threadIdx.x;
    if (t < 64) g[t] = gsum[t] / (float)N;
    __syncthreads();
    if (t < 200) {
        float acc = fcb[t];
#pragma unroll
        for (int c = 0; c < 64; c++) acc += g[c] * fcw[c * 200 + t];
        out[t] = acc;
    }
}

extern "C" void kernel_launch(void* const* d_in, const int* in_sizes, int n_in,
                              void* d_out, int out_size, void* d_ws, size_t ws_size,
                              hipStream_t stream) {
    const int* x = (const int*)d_in[0];
    const int* ei = (const int*)d_in[1];
    const int* et = (const int*)d_in[2];
    const float* ent_emb = (const float*)d_in[3];
    const float* rel_emb = (const float*)d_in[4];
    const float* W1 = (const float*)d_in[5];
    const float* a1s = (const float*)d_in[6];
    const float* a1d = (const float*)d_in[7];
    const float* b1 = (const float*)d_in[8];
    const float* W2 = (const float*)d_in[9];
    const float* a2s = (const float*)d_in[10];
    const float* a2d = (const float*)d_in[11];
    const float* b2 = (const float*)d_in[12];
    const float* fcw = (const float*)d_in[13];
    const float* fcb = (const float*)d_in[14];
    float* out = (float*)d_out;

    int N = in_sizes[0];
    int E = in_sizes[1] / 2;
    int Etot = E + N;
    int NB = (N + 255) / 256;

    char* p = (char*)d_ws;
    auto alloc = [&](size_t bytes) -> char* {
        char* r = p;
        p += (bytes + 255) & ~(size_t)255;
        return r;
    };
    unsigned short* h1b = (unsigned short*)alloc((size_t)N * 128 * 2);
    unsigned short* wsb = (unsigned short*)alloc(2048 * 2);
    unsigned short* W1t = (unsigned short*)alloc((size_t)512 * 128 * 2);
    unsigned short* W2t = (unsigned short*)alloc((size_t)64 * 576 * 2);
    float* als1 = (float*)alloc((size_t)N * 8 * 4);
    float* ald1 = (float*)alloc((size_t)N * 8 * 4);
    float* ex1  = (float*)alloc((size_t)Etot * 8 * 4);
    float* inv1 = (float*)alloc((size_t)N * 8 * 4);
    unsigned* Gu = (unsigned*)alloc((size_t)N * 512 * 4);   // G bf16 [N][8][128]
    unsigned short* h2  = (unsigned short*)alloc((size_t)N * 576 * 2);
    unsigned short* hl2 = (unsigned short*)alloc((size_t)N * 64 * 2);
    float* als2 = (float*)alloc((size_t)N * 4);
    float* ald2 = (float*)alloc((size_t)N * 4);
    float* ex2  = (float*)alloc((size_t)Etot * 4);
    float* inv2 = (float*)alloc((size_t)N * 4);
    float* out2 = (float*)alloc((size_t)N * 64 * 4);
    int* offs   = (int*)alloc((size_t)(N + 1) * 4);
    int* csr    = (int*)alloc((size_t)Etot * 4);
    int* bsum   = (int*)alloc((size_t)NB * 4);
    int* bbase  = (int*)alloc((size_t)NB * 4);
    // zero-init region: deg, cursor, gsum contiguous
    char* z0 = p;
    int* deg    = (int*)alloc((size_t)N * 4);
    int* cursor = (int*)alloc((size_t)N * 4);
    float* gsum = (float*)alloc(64 * 4);
    size_t zbytes = (size_t)(p - z0);

    int tb = 256;
    hipMemsetAsync(z0, 0, zbytes, stream);
    prep_k<<<(N * 128 + tb - 1) / tb, tb, 0, stream>>>(x, et, ei, ent_emb, rel_emb, W1, W2,
                                                       a1s, a1d, h1b, wsb, W1t, W2t, deg, N, E);
    attn1_k<<<(N + 127) / 128, 256, 0, stream>>>(h1b, wsb, als1, ald1, N);
    scanA_k<<<NB, 256, 0, stream>>>(deg, bsum, N);
    scanB_k<<<1, 64, 0, stream>>>(bsum, bbase, offs, NB, N, Etot);
    scanC_k<<<NB, 256, 0, stream>>>(deg, bbase, offs, N);
    fill_k<<<(Etot + tb - 1) / tb, tb, 0, stream>>>(ei, E, N, offs, cursor, csr);
    alpha1_k<<<(N + 31) / 32, 256, 0, stream>>>(als1, ald1, offs, csr, ex1, inv1, N);
    aggG_k<<<N, 64, 0, stream>>>((const unsigned*)h1b, ex1, inv1, offs, csr, Gu, (unsigned*)h2, N);
    gemmG_k<<<dim3((N + 127) / 128, 8), 256, 0, stream>>>((const unsigned short*)Gu, W1t, b1, h2, N);
    gemm2_k<<<(N + 127) / 128, 256, 0, stream>>>(h2, W2t, hl2, N);
    attn2_k<<<(N + tb - 1) / tb, tb, 0, stream>>>(hl2, a2s, a2d, als2, ald2, N);
    alpha2_k<<<(N + tb - 1) / tb, tb, 0, stream>>>(als2, ald2, offs, csr, ex2, inv2, N);
    agg2_k<<<(N + 7) / 8, 256, 0, stream>>>(hl2, ex2, inv2, b2, offs, csr, out2, N);
    colred_k<<<(N + 255) / 256, 256, 0, stream>>>(out2, gsum, N);
    final_k<<<1, 256, 0, stream>>>(gsum, fcw, fcb, out, N);
}

// Round 6
// 280.981 us; speedup vs baseline: 2.7643x; 1.0487x over previous
//
#include <hip/hip_runtime.h>
#include <math.h>

#define NEG_SLOPE 0.2f

typedef __attribute__((ext_vector_type(8))) short short8;   // 8 bf16 (4 VGPRs)
typedef __attribute__((ext_vector_type(4))) float f32x4;

// ---------- helpers ----------
__device__ __forceinline__ float lrelu(float v) { return v > 0.f ? v : NEG_SLOPE * v; }
__device__ __forceinline__ float elu(float v) { return v > 0.f ? v : (__expf(v) - 1.f); }
__device__ __forceinline__ unsigned short f2b(float f) {   // fp32 -> bf16 RNE
    unsigned u = __float_as_uint(f);
    return (unsigned short)((u + 0x7FFFu + ((u >> 16) & 1u)) >> 16);
}
__device__ __forceinline__ float blo(unsigned v) { return __uint_as_float(v << 16); }
__device__ __forceinline__ float bhi(unsigned v) { return __uint_as_float(v & 0xFFFF0000u); }
__device__ __forceinline__ unsigned packb(float a, float b) {
    return ((unsigned)f2b(b) << 16) | (unsigned)f2b(a);
}
// LDS xor-swizzle: 16B-chunk o within row r
__device__ __forceinline__ int sw(int r, int o) { return (o ^ (r & 7)) << 3; }

// ---------- prep: h1(bf16), wsb[16][128], W1t, W2t, degree count ----------
__global__ void prep_k(const int* __restrict__ x, const int* __restrict__ et,
                       const int* __restrict__ ei,
                       const float* __restrict__ ent_emb, const float* __restrict__ rel_emb,
                       const float* __restrict__ W1, const float* __restrict__ W2,
                       const float* __restrict__ a1s, const float* __restrict__ a1d,
                       unsigned short* __restrict__ h1b, unsigned short* __restrict__ wsb,
                       unsigned short* __restrict__ W1t, unsigned short* __restrict__ W2t,
                       int* __restrict__ deg, int N, int E) {
    int t = blockIdx.x * blockDim.x + threadIdx.x;
    if (t < N * 128) {
        int n = t >> 7, j = t & 127;
        float v = (j < 64) ? ent_emb[(size_t)x[n] * 64 + j]
                           : rel_emb[(size_t)et[n] * 64 + (j - 64)];
        h1b[t] = f2b(v);
    }
    if (t < 2048) {  // wsb[hh][k]: hh<8 -> W1.a1s head hh, hh>=8 -> W1.a1d head hh-8
        int hh = t >> 7, k = t & 127;
        int h = hh & 7;
        const float* aw = (hh < 8) ? a1s : a1d;
        const float* wr = W1 + (size_t)k * 512 + h * 64;
        float s_ = 0.f;
#pragma unroll 16
        for (int c = 0; c < 64; c++) s_ += wr[c] * aw[h * 64 + c];
        wsb[t] = f2b(s_);
    }
    if (t < 512 * 128) {  // W1t[n][k] = W1[k][n]
        int n = t >> 7, kk = t & 127;
        W1t[t] = f2b(W1[(size_t)kk * 512 + n]);
    }
    if (t < 64 * 576) {   // W2t[n][k] = W2[k][n]
        int n = t / 576, k = t % 576;
        W2t[t] = f2b(W2[(size_t)k * 64 + n]);
    }
    if (t < E + N) {      // degree (incl self-loop); deg[] pre-zeroed by memset
        int dst = t < E ? ei[E + t] : t - E;
        atomicAdd(&deg[dst], 1);
    }
}

// ---------- attn1 (MFMA): [als|ald][N,16] = h1[N,128] @ wsb[16,128]^T ----------
__global__ __launch_bounds__(256) void attn1_k(const unsigned short* __restrict__ A,
                                               const unsigned short* __restrict__ Bt,
                                               float* __restrict__ als, float* __restrict__ ald,
                                               int M) {
    __shared__ __align__(16) unsigned short As[128 * 128];
    __shared__ __align__(16) unsigned short Bs[16 * 128];
    int tid = threadIdx.x;
    int m0 = blockIdx.x * 128;
    for (int c = tid; c < 2048; c += 256) {
        int r = c >> 4, o = c & 15;
        int gr = m0 + r;
        uint4 v = make_uint4(0u, 0u, 0u, 0u);
        if (gr < M) v = *(const uint4*)(A + (size_t)gr * 128 + o * 8);
        *(uint4*)(As + r * 128 + sw(r, o)) = v;
    }
    if (tid < 256) {
        int r = tid >> 4, o = tid & 15;
        uint4 v = *(const uint4*)(Bt + (size_t)r * 128 + o * 8);
        *(uint4*)(Bs + r * 128 + sw(r, o)) = v;
    }
    __syncthreads();
    int w = tid >> 6, lane = tid & 63;
    int wr = w * 32;
    int m16 = lane & 15, quad = lane >> 4;
    f32x4 acc[2] = {};
#pragma unroll
    for (int kk = 0; kk < 128; kk += 32) {
        int ob = (kk >> 3) + quad;
        short8 b = *(const short8*)(Bs + m16 * 128 + sw(m16, ob));
#pragma unroll
        for (int i = 0; i < 2; i++) {
            int r = wr + i * 16 + m16;
            short8 a = *(const short8*)(As + r * 128 + sw(r, ob));
            acc[i] = __builtin_amdgcn_mfma_f32_16x16x32_bf16(a, b, acc[i], 0, 0, 0);
        }
    }
#pragma unroll
    for (int i = 0; i < 2; i++)
#pragma unroll
        for (int reg = 0; reg < 4; reg++) {
            int row = m0 + wr + i * 16 + quad * 4 + reg;
            if (row < M) {
                if (m16 < 8) als[row * 8 + m16] = acc[i][reg];
                else         ald[row * 8 + (m16 - 8)] = acc[i][reg];
            }
        }
}

// ---------- 3-phase parallel scan ----------
__global__ __launch_bounds__(256) void scanA_k(const int* __restrict__ deg,
                                               int* __restrict__ bsum, int N) {
    __shared__ int red[256];
    int t = threadIdx.x;
    int i = blockIdx.x * 256 + t;
    red[t] = (i < N) ? deg[i] : 0;
    __syncthreads();
    for (int off = 128; off > 0; off >>= 1) {
        if (t < off) red[t] += red[t + off];
        __syncthreads();
    }
    if (t == 0) bsum[blockIdx.x] = red[0];
}
__global__ void scanB_k(const int* __restrict__ bsum, int* __restrict__ bbase,
                        int* __restrict__ offs, int NB, int N, int Etot) {
    if (threadIdx.x == 0) {
        int run = 0;
        for (int i = 0; i < NB; i++) { bbase[i] = run; run += bsum[i]; }
        offs[N] = Etot;
    }
}
__global__ __launch_bounds__(256) void scanC_k(const int* __restrict__ deg,
                                               const int* __restrict__ bbase,
                                               int* __restrict__ offs, int N) {
    __shared__ int s[256];
    int t = threadIdx.x;
    int i = blockIdx.x * 256 + t;
    int v = (i < N) ? deg[i] : 0;
    s[t] = v;
    __syncthreads();
    for (int off = 1; off < 256; off <<= 1) {
        int tmp = (t >= off) ? s[t - off] : 0;
        __syncthreads();
        s[t] += tmp;
        __syncthreads();
    }
    if (i < N) offs[i] = bbase[blockIdx.x] + s[t] - v;
}

// ---------- CSR fill (src only) ----------
__global__ void fill_k(const int* __restrict__ ei, int E, int N,
                       const int* __restrict__ offs, int* __restrict__ cursor,
                       int* __restrict__ csr) {
    int e = blockIdx.x * blockDim.x + threadIdx.x;
    if (e >= E + N) return;
    int src = e < E ? ei[e] : e - E;
    int dst = e < E ? ei[E + e] : e - E;
    int pos = offs[dst] + atomicAdd(&cursor[dst], 1);
    csr[pos] = src;
}

// ---------- aggG: fused softmax + aggregate; G[n][h][k] bf16 ----------
// one wave per dst node; lane t: k = 2t,2t+1. Lane computes exp for head (t&7);
// broadcast to all lanes via shfl. 1 exp per lane per edge.
__global__ __launch_bounds__(64) void aggG_k(const unsigned* __restrict__ h1u,
                                             const float* __restrict__ als1,
                                             const float* __restrict__ ald1,
                                             const int* __restrict__ offs,
                                             const int* __restrict__ csr,
                                             unsigned* __restrict__ Gu, int N) {
    int n = blockIdx.x;
    int t = threadIdx.x;
    int hh = t & 7;
    float dl = ald1[n * 8 + hh];
    int p0 = offs[n], p1 = offs[n + 1];
    float a0[8] = {}, a1[8] = {};
    float ssacc = 0.f;
    for (int p = p0; p < p1; p++) {
        int src = csr[p];
        float x = __expf(lrelu(als1[src * 8 + hh] + dl));
        ssacc += x;
        unsigned hv = h1u[(size_t)src * 64 + t];
        float f0 = blo(hv), f1 = bhi(hv);
        float ev[8];
#pragma unroll
        for (int h = 0; h < 8; h++) ev[h] = __shfl(x, h, 64);
#pragma unroll
        for (int h = 0; h < 8; h++) {
            a0[h] += ev[h] * f0;
            a1[h] += ev[h] * f1;
        }
    }
#pragma unroll
    for (int h = 0; h < 8; h++) {
        float iv = 1.f / (__shfl(ssacc, h, 64) + 1e-16f);
        Gu[(size_t)n * 512 + h * 64 + t] = packb(a0[h] * iv, a1[h] * iv);
    }
}

// ---------- gemmF: fused gemmG + gemm2; h2-tile lives in LDS only ----------
// block = 256 thr / 4 waves, 64 nodes. Phase1: h2t[64][576+pad] = [elu(G@W1t+b1)|ent].
// Phase2: hl2[64][64] = h2t @ W2t^T.
#define H2LD 584
__global__ __launch_bounds__(256) void gemmF_k(const unsigned short* __restrict__ Gb,
                                               const unsigned short* __restrict__ W1t,
                                               const unsigned short* __restrict__ W2t,
                                               const float* __restrict__ b1,
                                               const unsigned* __restrict__ h1u,
                                               unsigned short* __restrict__ hl2, int M) {
    __shared__ __align__(16) unsigned short h2t[64 * H2LD];
    int tid = threadIdx.x;
    int m0 = blockIdx.x * 64;
    int w = tid >> 6, lane = tid & 63;
    int m16 = lane & 15, quad = lane >> 4;
    int rowl = w * 16 + m16;
    int growA = m0 + rowl; if (growA > M - 1) growA = M - 1;   // clamp (stores guarded)
    // phase 1: 8 heads, each 16x64 out per wave
    for (int h = 0; h < 8; h++) {
        f32x4 acc[4] = {};
#pragma unroll
        for (int ks = 0; ks < 4; ks++) {
            short8 a = *(const short8*)(Gb + (size_t)growA * 1024 + h * 128 + ks * 32 + quad * 8);
#pragma unroll
            for (int j = 0; j < 4; j++) {
                short8 b = *(const short8*)(W1t + (size_t)(h * 64 + j * 16 + m16) * 128 + ks * 32 + quad * 8);
                acc[j] = __builtin_amdgcn_mfma_f32_16x16x32_bf16(a, b, acc[j], 0, 0, 0);
            }
        }
#pragma unroll
        for (int j = 0; j < 4; j++) {
            int col = h * 64 + j * 16 + m16;
            float bb = b1[col];
#pragma unroll
            for (int reg = 0; reg < 4; reg++) {
                int r = w * 16 + quad * 4 + reg;
                h2t[r * H2LD + col] = f2b(elu(acc[j][reg] + bb));
            }
        }
    }
    // ent tail: cols 512..575 = h1 cols 0..63 (as 32 u32 per row)
    for (int c = tid; c < 64 * 32; c += 256) {
        int r = c >> 5, cc = c & 31;
        int gr = m0 + r; if (gr > M - 1) gr = M - 1;
        unsigned v = h1u[(size_t)gr * 64 + cc];
        *(unsigned*)(h2t + r * H2LD + 512 + 2 * cc) = v;
    }
    __syncthreads();
    // phase 2: hl2 tile
    f32x4 acc2[4] = {};
    for (int ks = 0; ks < 18; ks++) {
        short8 a = *(const short8*)(h2t + rowl * H2LD + ks * 32 + quad * 8);
#pragma unroll
        for (int j = 0; j < 4; j++) {
            short8 b = *(const short8*)(W2t + (size_t)(j * 16 + m16) * 576 + ks * 32 + quad * 8);
            acc2[j] = __builtin_amdgcn_mfma_f32_16x16x32_bf16(a, b, acc2[j], 0, 0, 0);
        }
    }
#pragma unroll
    for (int j = 0; j < 4; j++)
#pragma unroll
        for (int reg = 0; reg < 4; reg++) {
            int row = m0 + w * 16 + quad * 4 + reg;
            int col = j * 16 + m16;
            if (row < M) hl2[(size_t)row * 64 + col] = f2b(acc2[j][reg]);
        }
}

// ---------- layer2 attn logits ----------
__global__ void attn2_k(const unsigned short* __restrict__ hl, const float* __restrict__ aw_s,
                        const float* __restrict__ aw_d, float* __restrict__ als,
                        float* __restrict__ ald, int N) {
    int t = blockIdx.x * blockDim.x + threadIdx.x;
    if (t >= N) return;
    const unsigned short* row = hl + (size_t)t * 64;
    float s_ = 0.f, d_ = 0.f;
#pragma unroll
    for (int c = 0; c < 64; c += 2) {
        unsigned v = *(const unsigned*)(row + c);
        float f0 = blo(v), f1 = bhi(v);
        s_ += f0 * aw_s[c] + f1 * aw_s[c + 1];
        d_ += f0 * aw_d[c] + f1 * aw_d[c + 1];
    }
    als[t] = s_;
    ald[t] = d_;
}

// ---------- agg2: fused softmax+aggregate+elu, emits per-block column partials ----------
// 256 threads = 8 node-slots x 32 lanes
__global__ __launch_bounds__(256) void agg2_k(const unsigned short* __restrict__ hl2,
                                              const float* __restrict__ als2,
                                              const float* __restrict__ ald2,
                                              const float* __restrict__ b2,
                                              const int* __restrict__ offs,
                                              const int* __restrict__ csr,
                                              float* __restrict__ gpart, int N) {
    __shared__ float red[512];
    int slot = threadIdx.x >> 5, l = threadIdx.x & 31;
    int n = blockIdx.x * 8 + slot;
    float v0 = 0.f, v1 = 0.f;
    if (n < N) {
        float dl = ald2[n];
        int p0 = offs[n], p1 = offs[n + 1];
        float a0 = 0.f, a1 = 0.f, ssum = 0.f;
        for (int p = p0; p < p1; p++) {
            int src = csr[p];
            float xv = __expf(lrelu(als2[src] + dl));
            ssum += xv;
            unsigned v = *(const unsigned*)(hl2 + (size_t)src * 64 + 2 * l);
            a0 += xv * blo(v);
            a1 += xv * bhi(v);
        }
        float inv = 1.f / (ssum + 1e-16f);
        v0 = elu(a0 * inv + b2[2 * l]);
        v1 = elu(a1 * inv + b2[2 * l + 1]);
    }
    red[slot * 64 + 2 * l] = v0;
    red[slot * 64 + 2 * l + 1] = v1;
    __syncthreads();
    if (threadIdx.x < 64) {
        float s = 0.f;
#pragma unroll
        for (int ss = 0; ss < 8; ss++) s += red[ss * 64 + threadIdx.x];
        gpart[(size_t)blockIdx.x * 64 + threadIdx.x] = s;
    }
}

// ---------- reduce gpart -> gsum (atomics, gsum pre-zeroed) ----------
__global__ __launch_bounds__(256) void colred_k(const float* __restrict__ gpart,
                                                float* __restrict__ gsum, int NBL) {
    __shared__ float red[256];
    int t = threadIdx.x;
    int c = t & 63, rg = t >> 6;
    int bend = blockIdx.x * 256 + 256; if (bend > NBL) bend = NBL;
    float acc = 0.f;
    for (int b = blockIdx.x * 256 + rg; b < bend; b += 4)
        acc += gpart[(size_t)b * 64 + c];
    red[t] = acc;
    __syncthreads();
    if (t < 64) atomicAdd(&gsum[c], red[c] + red[c + 64] + red[c + 128] + red[c + 192]);
}

// ---------- final linear ----------
__global__ __launch_bounds__(256) void final_k(const float* __restrict__ gsum,
                                               const float* __restrict__ fcw,
                                               const float* __restrict__ fcb,
                                               float* __restrict__ out, int N) {
    __shared__ float g[64];
    int t = threadIdx.x;
    if (t < 64) g[t] = gsum[t] / (float)N;
    __syncthreads();
    if (t < 200) {
        float acc = fcb[t];
#pragma unroll
        for (int c = 0; c < 64; c++) acc += g[c] * fcw[c * 200 + t];
        out[t] = acc;
    }
}

extern "C" void kernel_launch(void* const* d_in, const int* in_sizes, int n_in,
                              void* d_out, int out_size, void* d_ws, size_t ws_size,
                              hipStream_t stream) {
    const int* x = (const int*)d_in[0];
    const int* ei = (const int*)d_in[1];
    const int* et = (const int*)d_in[2];
    const float* ent_emb = (const float*)d_in[3];
    const float* rel_emb = (const float*)d_in[4];
    const float* W1 = (const float*)d_in[5];
    const float* a1s = (const float*)d_in[6];
    const float* a1d = (const float*)d_in[7];
    const float* b1 = (const float*)d_in[8];
    const float* W2 = (const float*)d_in[9];
    const float* a2s = (const float*)d_in[10];
    const float* a2d = (const float*)d_in[11];
    const float* b2 = (const float*)d_in[12];
    const float* fcw = (const float*)d_in[13];
    const float* fcb = (const float*)d_in[14];
    float* out = (float*)d_out;

    int N = in_sizes[0];
    int E = in_sizes[1] / 2;
    int Etot = E + N;
    int NB = (N + 255) / 256;     // scan blocks
    int NBL = (N + 7) / 8;        // agg2 blocks

    char* p = (char*)d_ws;
    auto alloc = [&](size_t bytes) -> char* {
        char* r = p;
        p += (bytes + 255) & ~(size_t)255;
        return r;
    };
    unsigned short* h1b = (unsigned short*)alloc((size_t)N * 128 * 2);
    unsigned short* wsb = (unsigned short*)alloc(2048 * 2);
    unsigned short* W1t = (unsigned short*)alloc((size_t)512 * 128 * 2);
    unsigned short* W2t = (unsigned short*)alloc((size_t)64 * 576 * 2);
    float* als1 = (float*)alloc((size_t)N * 8 * 4);
    float* ald1 = (float*)alloc((size_t)N * 8 * 4);
    unsigned* Gu = (unsigned*)alloc((size_t)N * 512 * 4);   // G bf16 [N][8][128]
    unsigned short* hl2 = (unsigned short*)alloc((size_t)N * 64 * 2);
    float* als2 = (float*)alloc((size_t)N * 4);
    float* ald2 = (float*)alloc((size_t)N * 4);
    float* gpart = (float*)alloc((size_t)NBL * 64 * 4);
    int* offs   = (int*)alloc((size_t)(N + 1) * 4);
    int* csr    = (int*)alloc((size_t)Etot * 4);
    int* bsum   = (int*)alloc((size_t)NB * 4);
    int* bbase  = (int*)alloc((size_t)NB * 4);
    // zero-init region: deg, cursor, gsum contiguous
    char* z0 = p;
    int* deg    = (int*)alloc((size_t)N * 4);
    int* cursor = (int*)alloc((size_t)N * 4);
    float* gsum = (float*)alloc(64 * 4);
    size_t zbytes = (size_t)(p - z0);

    int tb = 256;
    hipMemsetAsync(z0, 0, zbytes, stream);
    prep_k<<<(N * 128 + tb - 1) / tb, tb, 0, stream>>>(x, et, ei, ent_emb, rel_emb, W1, W2,
                                                       a1s, a1d, h1b, wsb, W1t, W2t, deg, N, E);
    attn1_k<<<(N + 127) / 128, 256, 0, stream>>>(h1b, wsb, als1, ald1, N);
    scanA_k<<<NB, 256, 0, stream>>>(deg, bsum, N);
    scanB_k<<<1, 64, 0, stream>>>(bsum, bbase, offs, NB, N, Etot);
    scanC_k<<<NB, 256, 0, stream>>>(deg, bbase, offs, N);
    fill_k<<<(Etot + tb - 1) / tb, tb, 0, stream>>>(ei, E, N, offs, cursor, csr);
    aggG_k<<<N, 64, 0, stream>>>((const unsigned*)h1b, als1, ald1, offs, csr, Gu, N);
    gemmF_k<<<(N + 63) / 64, 256, 0, stream>>>((const unsigned short*)Gu, W1t, W2t, b1,
                                               (const unsigned*)h1b, hl2, N);
    attn2_k<<<(N + tb - 1) / tb, tb, 0, stream>>>(hl2, a2s, a2d, als2, ald2, N);
    agg2_k<<<NBL, 256, 0, stream>>>(hl2, als2, ald2, b2, offs, csr, gpart, N);
    colred_k<<<(NBL + 255) / 256, 256, 0, stream>>>(gpart, gsum, NBL);
    final_k<<<1, 256, 0, stream>>>(gsum, fcw, fcb, out, N);
}